// Round 1
// baseline (255.420 us; speedup 1.0000x reference)
//
#include <hip/hip_runtime.h>

typedef __bf16 bf16_t;
typedef __bf16 bf16x4 __attribute__((ext_vector_type(4)));
typedef __bf16 bf16x8 __attribute__((ext_vector_type(8)));
typedef float  f32x4  __attribute__((ext_vector_type(4)));

// Problem constants (setup_inputs: b=2, t=8, C=768, h=w=16)
static constexpr int NHEADS = 12, HC = 64, HW = 256, SEQ = 2048;
static constexpr size_t QKV_ONE = (size_t)2 * NHEADS * SEQ * HC;   // 3145728 elems per q/k/v slab
static constexpr size_t NSTRIDE = 768 * 256;                        // 196608

// ---------------------------------------------------------------------------
// prep: blocks 0..3071 = mp_weight rows (wqkv then wproj, proj columns
// permuted to j=head*64+c); blocks 3072..6143 = x fp32->bf16 transpose tiles.
// ---------------------------------------------------------------------------
__global__ __launch_bounds__(256) void va_prep(const float* __restrict__ wqkv,
                                               const float* __restrict__ wproj,
                                               const float* __restrict__ x,
                                               bf16_t* __restrict__ wout,
                                               bf16_t* __restrict__ xt) {
    int blk = blockIdx.x;
    if (blk < 3072) {
        int row = blk;
        bool is_proj = (row >= 2304);
        const float* wr = is_proj ? wproj + (size_t)(row - 2304) * 768
                                  : wqkv + (size_t)row * 768;
        float part = 0.f;
        for (int i = threadIdx.x; i < 768; i += 256) { float v = wr[i]; part += v * v; }
#pragma unroll
        for (int off = 32; off > 0; off >>= 1) part += __shfl_down(part, off, 64);
        __shared__ float red[4];
        if ((threadIdx.x & 63) == 0) red[threadIdx.x >> 6] = part;
        __syncthreads();
        if (threadIdx.x == 0) {
            float s = red[0] + red[1] + red[2] + red[3];
            red[0] = 1.0f / (2.7712813e-3f + sqrtf(s));   // EPS*sqrt(768) + ||w||
        }
        __syncthreads();
        float sc = red[0];
        for (int i = threadIdx.x; i < 768; i += 256) {
            int j = is_proj ? ((i % 12) * 64 + i / 12) : i;
            wout[(size_t)row * 768 + j] = (bf16_t)(wr[i] * sc);
        }
    } else {
        int t = blk - 3072;                 // [0, 3072)
        int n  = t & 15;
        int rest = t >> 4;                  // [0,192)
        int p0 = (rest & 7) * 32;
        int c0 = (rest >> 3) * 32;          // [0,24) * 32
        __shared__ float sm[32][33];
        int tx = threadIdx.x & 31, ty = threadIdx.x >> 5;
        const float* xp = x + (size_t)n * NSTRIDE;
#pragma unroll
        for (int i = 0; i < 4; i++)
            sm[ty + i * 8][tx] = xp[(size_t)(c0 + ty + i * 8) * 256 + p0 + tx];
        __syncthreads();
        bf16_t* xo = xt + (size_t)n * NSTRIDE;
#pragma unroll
        for (int i = 0; i < 4; i++)
            xo[(size_t)(p0 + ty + i * 8) * 768 + c0 + tx] = (bf16_t)sm[tx][ty + i * 8];
    }
}

// ---------------------------------------------------------------------------
// QKV GEMM via MFMA, RoPE + q-scale fused. XCD-remapped by n.
// v2: depth-2 register prefetch (3 rolling fragment buffers, k unrolled x3).
// The kernel was latency-bound (MfmaUtil 7%, VALUBusy 3%, occupancy fixed at
// 2.25 waves/SIMD by the 576-block grid) — loads were issued in the same
// k-step they were consumed. launch_bounds relaxed (256,2) so the ~96 extra
// fragment VGPRs don't spill; resident waves are block-limited anyway.
// ---------------------------------------------------------------------------
__global__ __launch_bounds__(256, 2) void va_qkv_mfma(const bf16_t* __restrict__ Wb,
                                                      const bf16_t* __restrict__ xt,
                                                      bf16_t* __restrict__ qkvb) {
    int idx = blockIdx.x;                   // [0,576)
    int n  = (idx & 7) + 8 * ((idx >> 3) & 1);
    int rest = idx >> 4;                    // [0,36)
    int p0 = (rest & 1) * 128;
    int m0 = (rest >> 1) * 128;             // [0,18)*128
    int tid = threadIdx.x;
    int lane = tid & 63, w = tid >> 6;
    int lo = lane & 15, hi = lane >> 4;
    int wm = w >> 1, wn = w & 1;

    const bf16_t* Ap = Wb + (size_t)(m0 + wm * 64 + lo) * 768 + hi * 8;
    const bf16_t* Bp = xt + (size_t)n * NSTRIDE + (size_t)(p0 + wn * 64 + lo) * 768 + hi * 8;

    f32x4 acc[4][4];
#pragma unroll
    for (int mt = 0; mt < 4; mt++)
#pragma unroll
        for (int nt = 0; nt < 4; nt++) acc[mt][nt] = (f32x4){0.f, 0.f, 0.f, 0.f};

    bf16x8 a0[4], b0[4], a1[4], b1[4], a2[4], b2[4];

    auto ld = [&](bf16x8 (&A)[4], bf16x8 (&B)[4], int K) {
#pragma unroll
        for (int mt = 0; mt < 4; mt++)
            A[mt] = *(const bf16x8*)(Ap + (size_t)mt * 16 * 768 + K);
#pragma unroll
        for (int nt = 0; nt < 4; nt++)
            B[nt] = *(const bf16x8*)(Bp + (size_t)nt * 16 * 768 + K);
    };
    auto mm = [&](bf16x8 (&A)[4], bf16x8 (&B)[4]) {
#pragma unroll
        for (int mt = 0; mt < 4; mt++)
#pragma unroll
            for (int nt = 0; nt < 4; nt++)
                acc[mt][nt] = __builtin_amdgcn_mfma_f32_16x16x32_bf16(A[mt], B[nt], acc[mt][nt], 0, 0, 0);
    };

    ld(a0, b0, 0);
    ld(a1, b1, 32);
    for (int k0 = 0; k0 < 768; k0 += 96) {
        // prefetch clamps: out-of-range loads fetch k=0 (valid addr, never consumed)
        int k2 = k0 + 64;  if (k2 >= 768) k2 = 0;
        ld(a2, b2, k2);  mm(a0, b0);
        int k3 = k0 + 96;  if (k3 >= 768) k3 = 0;
        ld(a0, b0, k3);  mm(a1, b1);
        int k4 = k0 + 128; if (k4 >= 768) k4 = 0;
        ld(a1, b1, k4);  mm(a2, b2);
    }

    int head_global = (m0 + wm * 64) >> 6;
    int qkv_idx = head_global / 12;
    int head    = head_global % 12;
    int b = n >> 3, tt = n & 7;
    int bm = b * 12 + head;
    if (qkv_idx < 2) {
        float qsc = (qkv_idx == 0) ? 0.125f : 1.0f;
        float ttf = (float)tt;
#pragma unroll
        for (int mt = 0; mt < 2; mt++)
#pragma unroll
            for (int r = 0; r < 4; r++) {
                int j = mt * 16 + hi * 4 + r;
                float ang = ttf * __expf(-(float)j * 0.2878231366242557f);
                float cs = __cosf(ang), sn = __sinf(ang);
#pragma unroll
                for (int nt = 0; nt < 4; nt++) {
                    float x1 = acc[mt][nt][r], x2 = acc[mt + 2][nt][r];
                    acc[mt][nt][r]     = (x1 * cs - x2 * sn) * qsc;
                    acc[mt + 2][nt][r] = (x1 * sn + x2 * cs) * qsc;
                }
            }
        bf16_t* dst = qkvb + (size_t)qkv_idx * QKV_ONE + ((size_t)bm * SEQ + (size_t)tt * HW) * HC;
#pragma unroll
        for (int mt = 0; mt < 4; mt++)
#pragma unroll
            for (int nt = 0; nt < 4; nt++)
#pragma unroll
                for (int r = 0; r < 4; r++) {
                    int cc = mt * 16 + hi * 4 + r;
                    int p  = p0 + wn * 64 + nt * 16 + lo;
                    dst[(size_t)p * HC + cc] = (bf16_t)acc[mt][nt][r];
                }
    } else {
        bf16_t* dst = qkvb + 2 * QKV_ONE + (size_t)bm * HC * SEQ + (size_t)tt * HW;
#pragma unroll
        for (int mt = 0; mt < 4; mt++)
#pragma unroll
            for (int nt = 0; nt < 4; nt++)
#pragma unroll
                for (int r = 0; r < 4; r++) {
                    int cc = mt * 16 + hi * 4 + r;
                    int p  = p0 + wn * 64 + nt * 16 + lo;
                    dst[(size_t)cc * SEQ + p] = (bf16_t)acc[mt][nt][r];
                }
    }
}

// ---------------------------------------------------------------------------
// MFMA flash attention v8: BARRIER-FREE. (unchanged)
// ---------------------------------------------------------------------------
__global__ __launch_bounds__(256, 3) void va_attn(const bf16_t* __restrict__ qkvb,
                                                  bf16_t* __restrict__ Opart,
                                                  float* __restrict__ lpart) {
    int idx = blockIdx.x;                   // [0,864)
    int g = idx >> 3;                       // [0,108)
    int bm = (idx & 7) + 8 * (g / 36);      // same-bm -> same idx%8 -> same XCD
    int pidx = g % 36;                      // (f, kf<=f)
    int f = 0;
    while ((f + 1) * (f + 2) / 2 <= pidx) f++;
    int kf = pidx - f * (f + 1) / 2;

    int tid = threadIdx.x;
    int w = tid >> 6, lane = tid & 63;
    int lo = lane & 15, hi = lane >> 4;
    int lx = lo & 7;               // swizzle key

    const bf16_t* qbase = qkvb + (size_t)bm * SEQ * HC;
    const bf16_t* kbase = qkvb + QKV_ONE + (size_t)bm * SEQ * HC;
    const bf16_t* vbase = qkvb + 2 * QKV_ONE + (size_t)bm * HC * SEQ;

    __shared__ bf16_t PBF[4][64 * 64];      // wave-private P^T / O transpose
    bf16_t* PBw = PBF[w];

    // Q B-frags: wave w owns queries f*256 + w*64 .. +63 (q pre-scaled 0.125)
    const bf16_t* qrow = qbase + (size_t)(f * 256 + w * 64 + lo) * HC;
    bf16x8 qf[4][2];
#pragma unroll
    for (int nq = 0; nq < 4; nq++) {
        qf[nq][0] = *(const bf16x8*)(qrow + (size_t)nq * 16 * HC + hi * 8);
        qf[nq][1] = *(const bf16x8*)(qrow + (size_t)nq * 16 * HC + 32 + hi * 8);
    }
    f32x4 o[4][4];
#pragma unroll
    for (int ct = 0; ct < 4; ct++)
#pragma unroll
        for (int nq = 0; nq < 4; nq++) o[ct][nq] = (f32x4){0.f, 0.f, 0.f, 0.f};
    float l4[4] = {0.f, 0.f, 0.f, 0.f};

    for (int kt = 0; kt < 4; kt++) {
        int kpos = kf * 256 + kt * 64;      // absolute key base of this tile
        // ---- K fragments direct from global (wave covers full 64B sectors)
        const bf16_t* kp = kbase + (size_t)(kpos + lo) * HC + hi * 8;
        bf16x8 ka[8];
#pragma unroll
        for (int mt = 0; mt < 4; mt++) {
            ka[2 * mt]     = *(const bf16x8*)(kp + (size_t)mt * 16 * HC);
            ka[2 * mt + 1] = *(const bf16x8*)(kp + (size_t)mt * 16 * HC + 32);
        }
        // ---- S^T = K·Q^T, exp, P^T -> wave-private LDS
#pragma unroll
        for (int mt = 0; mt < 4; mt++) {
#pragma unroll
            for (int nq = 0; nq < 4; nq++) {
                f32x4 s = (f32x4){0.f, 0.f, 0.f, 0.f};
                s = __builtin_amdgcn_mfma_f32_16x16x32_bf16(ka[2 * mt], qf[nq][0], s, 0, 0, 0);
                s = __builtin_amdgcn_mfma_f32_16x16x32_bf16(ka[2 * mt + 1], qf[nq][1], s, 0, 0, 0);
                bf16x4 pk;
#pragma unroll
                for (int r = 0; r < 4; r++) {
                    float p = __expf(s[r]);
                    l4[nq] += p;
                    pk[r] = (bf16_t)p;
                }
                *(bf16x4*)(PBw + (nq * 16 + lo) * 64 +
                           (((2 * mt + (hi >> 1)) ^ lx) * 8) + (hi & 1) * 4) = pk;
            }
        }
        // ---- V fragments direct from global (transposed slab)
        const bf16_t* vp = vbase + (size_t)(lo) * SEQ + kpos + hi * 8;
        bf16x8 va[8];
#pragma unroll
        for (int ct = 0; ct < 4; ct++) {
            va[2 * ct]     = *(const bf16x8*)(vp + (size_t)ct * 16 * SEQ);
            va[2 * ct + 1] = *(const bf16x8*)(vp + (size_t)ct * 16 * SEQ + 32);
        }
        // ---- P^T B-frags back from LDS (same wave, DS in-order)
        bf16x8 pb0[4], pb1[4];
#pragma unroll
        for (int nq = 0; nq < 4; nq++) {
            pb0[nq] = *(const bf16x8*)(PBw + (nq * 16 + lo) * 64 + (hi ^ lx) * 8);
            pb1[nq] = *(const bf16x8*)(PBw + (nq * 16 + lo) * 64 + ((4 + hi) ^ lx) * 8);
        }
        // ---- O^T += V^T·P^T
#pragma unroll
        for (int ct = 0; ct < 4; ct++)
#pragma unroll
            for (int nq = 0; nq < 4; nq++) {
                o[ct][nq] = __builtin_amdgcn_mfma_f32_16x16x32_bf16(va[2 * ct], pb0[nq], o[ct][nq], 0, 0, 0);
                o[ct][nq] = __builtin_amdgcn_mfma_f32_16x16x32_bf16(va[2 * ct + 1], pb1[nq], o[ct][nq], 0, 0, 0);
            }
    }
    // ---- l reduction + store
#pragma unroll
    for (int nq = 0; nq < 4; nq++) {
        l4[nq] += __shfl_xor(l4[nq], 16, 64);
        l4[nq] += __shfl_xor(l4[nq], 32, 64);
    }
    if (hi == 0) {
        float* lb = lpart + (size_t)(bm * 36 + pidx) * 256 + w * 64;
#pragma unroll
        for (int nq = 0; nq < 4; nq++) lb[nq * 16 + lo] = l4[nq];
    }
    // ---- O partial: wave-private LDS transpose -> dense bf16 [q][c] stores
#pragma unroll
    for (int ct = 0; ct < 4; ct++)
#pragma unroll
        for (int nq = 0; nq < 4; nq++) {
            bf16x4 ov;
#pragma unroll
            for (int r = 0; r < 4; r++) ov[r] = (bf16_t)o[ct][nq][r];
            *(bf16x4*)(PBw + (nq * 16 + lo) * 64 +
                       (((2 * ct + (hi >> 1)) ^ lx) * 8) + (hi & 1) * 4) = ov;
        }
    bf16_t* Ob = Opart + (size_t)(bm * 36 + pidx) * 16384 + (size_t)w * 4096;
#pragma unroll
    for (int i = 0; i < 8; i++) {
        int row = i * 8 + (lane >> 3);
        int j   = lane & 7;
        bf16x8 v = *(const bf16x8*)(PBw + row * 64 + ((j ^ (row & 7)) * 8));
        *(bf16x8*)(Ob + (size_t)row * 64 + j * 8) = v;
    }
}

// ---------------------------------------------------------------------------
// merge v4: XCD-remapped, one bf16x8 chunk per thread, dense. (unchanged)
// ---------------------------------------------------------------------------
__global__ __launch_bounds__(256) void va_merge(const bf16_t* __restrict__ Opart,
                                                const float* __restrict__ lpart,
                                                bf16_t* __restrict__ yob) {
    int idx = blockIdx.x;                   // [0,1536)
    int g = idx >> 3;                       // [0,192)
    int bm = (idx & 7) + 8 * (g >> 6);      // same-bm -> same XCD as attn
    int inner = g & 63;
    int rem = inner * 256 + threadIdx.x;    // [0,16384) chunk within bm
    int f    = rem >> 11;
    int rem2 = rem & 2047;
    int q    = rem2 >> 3;
    int c8   = rem2 & 7;
    int sbase = bm * 36 + f * (f + 1) / 2;

    float lsum = 0.f;
    for (int kf = 0; kf <= f; kf++)
        lsum += lpart[(size_t)(sbase + kf) * 256 + q];

    float v[8] = {0.f, 0.f, 0.f, 0.f, 0.f, 0.f, 0.f, 0.f};
    const bf16_t* Ob = Opart + (size_t)sbase * 16384 + (size_t)q * 64 + c8 * 8;
    for (int kf = 0; kf <= f; kf++) {
        bf16x8 pv = *(const bf16x8*)(Ob + (size_t)kf * 16384);
#pragma unroll
        for (int r = 0; r < 8; r++) v[r] += (float)pv[r];
    }

    float invl = 1.0f / lsum;
    int head = bm % 12, b = bm / 12;
    bf16x8 o8;
#pragma unroll
    for (int r = 0; r < 8; r++) o8[r] = (bf16_t)(v[r] * invl);
    *(bf16x8*)(yob + (size_t)(b * 8 + f) * NSTRIDE + (size_t)q * 768 + head * 64 + c8 * 8) = o8;
}

// ---------------------------------------------------------------------------
// Proj GEMM via MFMA + mp_sum. XCD-remapped by n.
// v2: 384 blocks (was 192 = 0.75 blocks/CU, a quarter of the chip idle).
// Block tile 64x128 (4 waves x 64x32 each, sharing the A rows via L1);
// depth-2 register prefetch identical to qkv v2.
// ---------------------------------------------------------------------------
__global__ __launch_bounds__(256, 2) void va_proj_mfma(const bf16_t* __restrict__ Wb,
                                                       const bf16_t* __restrict__ yob,
                                                       const float* __restrict__ x,
                                                       float* __restrict__ out) {
    int idx = blockIdx.x;                   // [0,384)
    int n  = (idx & 7) + 8 * ((idx >> 3) & 1);
    int rest = idx >> 4;                    // [0,24)
    int p0 = (rest & 1) * 128;
    int m0 = (rest >> 1) * 64;              // [0,12)*64
    int tid = threadIdx.x;
    int lane = tid & 63, w = tid >> 6;      // w = column-slice index [0,4)
    int lo = lane & 15, hi = lane >> 4;

    const bf16_t* Ap = Wb + (size_t)(m0 + lo) * 768 + hi * 8;
    const bf16_t* Bp = yob + (size_t)n * NSTRIDE + (size_t)(p0 + w * 32 + lo) * 768 + hi * 8;

    f32x4 acc[4][2];
#pragma unroll
    for (int mt = 0; mt < 4; mt++)
#pragma unroll
        for (int nt = 0; nt < 2; nt++) acc[mt][nt] = (f32x4){0.f, 0.f, 0.f, 0.f};

    bf16x8 a0[4], b0[2], a1[4], b1[2], a2[4], b2[2];

    auto ld = [&](bf16x8 (&A)[4], bf16x8 (&B)[2], int K) {
#pragma unroll
        for (int mt = 0; mt < 4; mt++)
            A[mt] = *(const bf16x8*)(Ap + (size_t)mt * 16 * 768 + K);
#pragma unroll
        for (int nt = 0; nt < 2; nt++)
            B[nt] = *(const bf16x8*)(Bp + (size_t)nt * 16 * 768 + K);
    };
    auto mm = [&](bf16x8 (&A)[4], bf16x8 (&B)[2]) {
#pragma unroll
        for (int mt = 0; mt < 4; mt++)
#pragma unroll
            for (int nt = 0; nt < 2; nt++)
                acc[mt][nt] = __builtin_amdgcn_mfma_f32_16x16x32_bf16(A[mt], B[nt], acc[mt][nt], 0, 0, 0);
    };

    ld(a0, b0, 0);
    ld(a1, b1, 32);
    for (int k0 = 0; k0 < 768; k0 += 96) {
        int k2 = k0 + 64;  if (k2 >= 768) k2 = 0;
        ld(a2, b2, k2);  mm(a0, b0);
        int k3 = k0 + 96;  if (k3 >= 768) k3 = 0;
        ld(a0, b0, k3);  mm(a1, b1);
        int k4 = k0 + 128; if (k4 >= 768) k4 = 0;
        ld(a1, b1, k4);  mm(a2, b2);
    }

    const float* xn = x + (size_t)n * NSTRIDE;
    float* on = out + (size_t)n * NSTRIDE;
#pragma unroll
    for (int mt = 0; mt < 4; mt++)
#pragma unroll
        for (int nt = 0; nt < 2; nt++)
#pragma unroll
            for (int r = 0; r < 4; r++) {
                int oo = m0 + mt * 16 + hi * 4 + r;
                int p  = p0 + w * 32 + nt * 16 + lo;
                size_t idx2 = (size_t)oo * 256 + p;
                on[idx2] = (xn[idx2] * 0.7f + acc[mt][nt][r] * 0.3f) * 1.3130643f;
            }
}

// ---------------------------------------------------------------------------
extern "C" void kernel_launch(void* const* d_in, const int* in_sizes, int n_in,
                              void* d_out, int out_size, void* d_ws, size_t ws_size,
                              hipStream_t stream) {
    const float* x     = (const float*)d_in[0];
    const float* wqkv  = (const float*)d_in[1];
    const float* wproj = (const float*)d_in[2];
    float* out = (float*)d_out;

    bf16_t* Opart = (bf16_t*)d_ws;                             // 24*36*16384 bf16
    float*  lpart = (float*)(Opart + (size_t)24 * 36 * 16384); // 24*36*256 fp32
    bf16_t* wqkv_nb  = (bf16_t*)(lpart + (size_t)24 * 36 * 256);
    bf16_t* xt       = wqkv_nb + (size_t)3072 * 768;
    bf16_t* qkvb     = xt + NSTRIDE * 16;
    bf16_t* yob      = qkvb + 3 * QKV_ONE;

    va_prep<<<6144, 256, 0, stream>>>(wqkv, wproj, x, wqkv_nb, xt);
    va_qkv_mfma<<<576, 256, 0, stream>>>(wqkv_nb, xt, qkvb);
    va_attn<<<864, 256, 0, stream>>>(qkvb, Opart, lpart);
    va_merge<<<1536, 256, 0, stream>>>(Opart, lpart, yob);
    va_proj_mfma<<<384, 256, 0, stream>>>(wqkv_nb + (size_t)2304 * 768, yob, x, out);
}

// Round 2
// 205.568 us; speedup vs baseline: 1.2425x; 1.2425x over previous
//
#include <hip/hip_runtime.h>

typedef __bf16 bf16_t;
typedef __bf16 bf16x4 __attribute__((ext_vector_type(4)));
typedef __bf16 bf16x8 __attribute__((ext_vector_type(8)));
typedef float  f32x4  __attribute__((ext_vector_type(4)));

// Problem constants (setup_inputs: b=2, t=8, C=768, h=w=16)
static constexpr int NHEADS = 12, HC = 64, HW = 256, SEQ = 2048;
static constexpr size_t QKV_ONE = (size_t)2 * NHEADS * SEQ * HC;   // 3145728 elems per q/k/v slab
static constexpr size_t NSTRIDE = 768 * 256;                        // 196608

// ---------------------------------------------------------------------------
// prep: blocks 0..3071 = mp_weight rows (wqkv then wproj, proj columns
// permuted to j=head*64+c); blocks 3072..6143 = x fp32->bf16 transpose tiles.
// ---------------------------------------------------------------------------
__global__ __launch_bounds__(256) void va_prep(const float* __restrict__ wqkv,
                                               const float* __restrict__ wproj,
                                               const float* __restrict__ x,
                                               bf16_t* __restrict__ wout,
                                               bf16_t* __restrict__ xt) {
    int blk = blockIdx.x;
    if (blk < 3072) {
        int row = blk;
        bool is_proj = (row >= 2304);
        const float* wr = is_proj ? wproj + (size_t)(row - 2304) * 768
                                  : wqkv + (size_t)row * 768;
        float part = 0.f;
        for (int i = threadIdx.x; i < 768; i += 256) { float v = wr[i]; part += v * v; }
#pragma unroll
        for (int off = 32; off > 0; off >>= 1) part += __shfl_down(part, off, 64);
        __shared__ float red[4];
        if ((threadIdx.x & 63) == 0) red[threadIdx.x >> 6] = part;
        __syncthreads();
        if (threadIdx.x == 0) {
            float s = red[0] + red[1] + red[2] + red[3];
            red[0] = 1.0f / (2.7712813e-3f + sqrtf(s));   // EPS*sqrt(768) + ||w||
        }
        __syncthreads();
        float sc = red[0];
        for (int i = threadIdx.x; i < 768; i += 256) {
            int j = is_proj ? ((i % 12) * 64 + i / 12) : i;
            wout[(size_t)row * 768 + j] = (bf16_t)(wr[i] * sc);
        }
    } else {
        int t = blk - 3072;                 // [0, 3072)
        int n  = t & 15;
        int rest = t >> 4;                  // [0,192)
        int p0 = (rest & 7) * 32;
        int c0 = (rest >> 3) * 32;          // [0,24) * 32
        __shared__ float sm[32][33];
        int tx = threadIdx.x & 31, ty = threadIdx.x >> 5;
        const float* xp = x + (size_t)n * NSTRIDE;
#pragma unroll
        for (int i = 0; i < 4; i++)
            sm[ty + i * 8][tx] = xp[(size_t)(c0 + ty + i * 8) * 256 + p0 + tx];
        __syncthreads();
        bf16_t* xo = xt + (size_t)n * NSTRIDE;
#pragma unroll
        for (int i = 0; i < 4; i++)
            xo[(size_t)(p0 + ty + i * 8) * 768 + c0 + tx] = (bf16_t)sm[tx][ty + i * 8];
    }
}

// ---------------------------------------------------------------------------
// QKV GEMM via MFMA, RoPE + q-scale fused. XCD-remapped by n.
// v3: LDS-staged (m97-family). v2's register prefetch was NEUTRAL (74->78us,
// MfmaUtil still 7%) -> kernel is L1-miss/segment bound: direct fragment
// loads touch 16 scattered 64B rows per inst, ~27k L1 misses per CU against
// a per-CU outstanding-miss cap. Fix: stage 128x64 A/B tiles in LDS once
// per BLOCK (coalesced 128B-aligned row reads, half the unique segments),
// serve fragments via ds_read_b128 with a chunk^(row&7) XOR swizzle
// (write+read sides) to avoid the 128B-stride bank conflict. Next tile's
// global loads issue early, hidden under current tile's MFMA (T14).
// ---------------------------------------------------------------------------
__global__ __launch_bounds__(256, 2) void va_qkv_mfma(const bf16_t* __restrict__ Wb,
                                                      const bf16_t* __restrict__ xt,
                                                      bf16_t* __restrict__ qkvb) {
    int idx = blockIdx.x;                   // [0,576)
    int n  = (idx & 7) + 8 * ((idx >> 3) & 1);
    int rest = idx >> 4;                    // [0,36)
    int p0 = (rest & 1) * 128;
    int m0 = (rest >> 1) * 128;             // [0,18)*128
    int tid = threadIdx.x;
    int lane = tid & 63, w = tid >> 6;
    int lo = lane & 15, hi = lane >> 4;
    int wm = w >> 1, wn = w & 1;
    int lx = lo & 7;                        // read-side swizzle key (= row&7)

    __shared__ bf16_t Asm[128 * 64];        // [row 0..127][k 0..63], 128B rows
    __shared__ bf16_t Bsm[128 * 64];

    // staging: thread t owns rows (t>>3)+32i, 16B chunk c=(t&7); dest chunk
    // is XOR-swizzled by row&7 (invariant under +32).
    int srow = tid >> 3, schunk = tid & 7;
    const bf16_t* Ag = Wb + (size_t)(m0 + srow) * 768 + schunk * 8;
    const bf16_t* Bg = xt + (size_t)n * NSTRIDE + (size_t)(p0 + srow) * 768 + schunk * 8;
    int sdst = srow * 128 + ((schunk ^ (srow & 7)) << 4);

    f32x4 acc[4][4];
#pragma unroll
    for (int mt = 0; mt < 4; mt++)
#pragma unroll
        for (int nt = 0; nt < 4; nt++) acc[mt][nt] = (f32x4){0.f, 0.f, 0.f, 0.f};

    bf16x8 sa[4], sb[4];                    // stage registers (4 rows each of A,B)

    auto gload = [&](int k0) {
#pragma unroll
        for (int i = 0; i < 4; i++) {
            sa[i] = *(const bf16x8*)(Ag + (size_t)i * 32 * 768 + k0);
            sb[i] = *(const bf16x8*)(Bg + (size_t)i * 32 * 768 + k0);
        }
    };
    auto swrite = [&]() {
        char* Ac = (char*)Asm;
        char* Bc = (char*)Bsm;
#pragma unroll
        for (int i = 0; i < 4; i++) {
            *(bf16x8*)(Ac + sdst + i * 32 * 128) = sa[i];
            *(bf16x8*)(Bc + sdst + i * 32 * 128) = sb[i];
        }
    };

    gload(0);
    for (int s = 0; s < 12; s++) {
        __syncthreads();                    // previous tile's ds_reads complete
        swrite();                           // (compiler waits vmcnt for sa/sb)
        if (s < 11) gload((s + 1) * 64);    // issue next tile early; drains
                                            // under this tile's MFMA
        __syncthreads();                    // tile visible
#pragma unroll
        for (int kk = 0; kk < 64; kk += 32) {
            int cb = kk >> 3;               // chunk base: 0 or 4
            bf16x8 af[4], bfr[4];
            const char* Ac = (const char*)Asm;
            const char* Bc = (const char*)Bsm;
#pragma unroll
            for (int mt = 0; mt < 4; mt++) {
                int row = wm * 64 + mt * 16 + lo;
                af[mt] = *(const bf16x8*)(Ac + row * 128 + (((cb + hi) ^ lx) << 4));
            }
#pragma unroll
            for (int nt = 0; nt < 4; nt++) {
                int row = wn * 64 + nt * 16 + lo;
                bfr[nt] = *(const bf16x8*)(Bc + row * 128 + (((cb + hi) ^ lx) << 4));
            }
#pragma unroll
            for (int mt = 0; mt < 4; mt++)
#pragma unroll
                for (int nt = 0; nt < 4; nt++)
                    acc[mt][nt] = __builtin_amdgcn_mfma_f32_16x16x32_bf16(af[mt], bfr[nt], acc[mt][nt], 0, 0, 0);
        }
    }

    int head_global = (m0 + wm * 64) >> 6;
    int qkv_idx = head_global / 12;
    int head    = head_global % 12;
    int b = n >> 3, tt = n & 7;
    int bm = b * 12 + head;
    if (qkv_idx < 2) {
        float qsc = (qkv_idx == 0) ? 0.125f : 1.0f;
        float ttf = (float)tt;
#pragma unroll
        for (int mt = 0; mt < 2; mt++)
#pragma unroll
            for (int r = 0; r < 4; r++) {
                int j = mt * 16 + hi * 4 + r;
                float ang = ttf * __expf(-(float)j * 0.2878231366242557f);
                float cs = __cosf(ang), sn = __sinf(ang);
#pragma unroll
                for (int nt = 0; nt < 4; nt++) {
                    float x1 = acc[mt][nt][r], x2 = acc[mt + 2][nt][r];
                    acc[mt][nt][r]     = (x1 * cs - x2 * sn) * qsc;
                    acc[mt + 2][nt][r] = (x1 * sn + x2 * cs) * qsc;
                }
            }
        bf16_t* dst = qkvb + (size_t)qkv_idx * QKV_ONE + ((size_t)bm * SEQ + (size_t)tt * HW) * HC;
#pragma unroll
        for (int mt = 0; mt < 4; mt++)
#pragma unroll
            for (int nt = 0; nt < 4; nt++)
#pragma unroll
                for (int r = 0; r < 4; r++) {
                    int cc = mt * 16 + hi * 4 + r;
                    int p  = p0 + wn * 64 + nt * 16 + lo;
                    dst[(size_t)p * HC + cc] = (bf16_t)acc[mt][nt][r];
                }
    } else {
        bf16_t* dst = qkvb + 2 * QKV_ONE + (size_t)bm * HC * SEQ + (size_t)tt * HW;
#pragma unroll
        for (int mt = 0; mt < 4; mt++)
#pragma unroll
            for (int nt = 0; nt < 4; nt++)
#pragma unroll
                for (int r = 0; r < 4; r++) {
                    int cc = mt * 16 + hi * 4 + r;
                    int p  = p0 + wn * 64 + nt * 16 + lo;
                    dst[(size_t)cc * SEQ + p] = (bf16_t)acc[mt][nt][r];
                }
    }
}

// ---------------------------------------------------------------------------
// MFMA flash attention v8: BARRIER-FREE. (unchanged)
// ---------------------------------------------------------------------------
__global__ __launch_bounds__(256, 3) void va_attn(const bf16_t* __restrict__ qkvb,
                                                  bf16_t* __restrict__ Opart,
                                                  float* __restrict__ lpart) {
    int idx = blockIdx.x;                   // [0,864)
    int g = idx >> 3;                       // [0,108)
    int bm = (idx & 7) + 8 * (g / 36);      // same-bm -> same idx%8 -> same XCD
    int pidx = g % 36;                      // (f, kf<=f)
    int f = 0;
    while ((f + 1) * (f + 2) / 2 <= pidx) f++;
    int kf = pidx - f * (f + 1) / 2;

    int tid = threadIdx.x;
    int w = tid >> 6, lane = tid & 63;
    int lo = lane & 15, hi = lane >> 4;
    int lx = lo & 7;               // swizzle key

    const bf16_t* qbase = qkvb + (size_t)bm * SEQ * HC;
    const bf16_t* kbase = qkvb + QKV_ONE + (size_t)bm * SEQ * HC;
    const bf16_t* vbase = qkvb + 2 * QKV_ONE + (size_t)bm * HC * SEQ;

    __shared__ bf16_t PBF[4][64 * 64];      // wave-private P^T / O transpose
    bf16_t* PBw = PBF[w];

    // Q B-frags: wave w owns queries f*256 + w*64 .. +63 (q pre-scaled 0.125)
    const bf16_t* qrow = qbase + (size_t)(f * 256 + w * 64 + lo) * HC;
    bf16x8 qf[4][2];
#pragma unroll
    for (int nq = 0; nq < 4; nq++) {
        qf[nq][0] = *(const bf16x8*)(qrow + (size_t)nq * 16 * HC + hi * 8);
        qf[nq][1] = *(const bf16x8*)(qrow + (size_t)nq * 16 * HC + 32 + hi * 8);
    }
    f32x4 o[4][4];
#pragma unroll
    for (int ct = 0; ct < 4; ct++)
#pragma unroll
        for (int nq = 0; nq < 4; nq++) o[ct][nq] = (f32x4){0.f, 0.f, 0.f, 0.f};
    float l4[4] = {0.f, 0.f, 0.f, 0.f};

    for (int kt = 0; kt < 4; kt++) {
        int kpos = kf * 256 + kt * 64;      // absolute key base of this tile
        // ---- K fragments direct from global (wave covers full 64B sectors)
        const bf16_t* kp = kbase + (size_t)(kpos + lo) * HC + hi * 8;
        bf16x8 ka[8];
#pragma unroll
        for (int mt = 0; mt < 4; mt++) {
            ka[2 * mt]     = *(const bf16x8*)(kp + (size_t)mt * 16 * HC);
            ka[2 * mt + 1] = *(const bf16x8*)(kp + (size_t)mt * 16 * HC + 32);
        }
        // ---- S^T = K·Q^T, exp, P^T -> wave-private LDS
#pragma unroll
        for (int mt = 0; mt < 4; mt++) {
#pragma unroll
            for (int nq = 0; nq < 4; nq++) {
                f32x4 s = (f32x4){0.f, 0.f, 0.f, 0.f};
                s = __builtin_amdgcn_mfma_f32_16x16x32_bf16(ka[2 * mt], qf[nq][0], s, 0, 0, 0);
                s = __builtin_amdgcn_mfma_f32_16x16x32_bf16(ka[2 * mt + 1], qf[nq][1], s, 0, 0, 0);
                bf16x4 pk;
#pragma unroll
                for (int r = 0; r < 4; r++) {
                    float p = __expf(s[r]);
                    l4[nq] += p;
                    pk[r] = (bf16_t)p;
                }
                *(bf16x4*)(PBw + (nq * 16 + lo) * 64 +
                           (((2 * mt + (hi >> 1)) ^ lx) * 8) + (hi & 1) * 4) = pk;
            }
        }
        // ---- V fragments direct from global (transposed slab)
        const bf16_t* vp = vbase + (size_t)(lo) * SEQ + kpos + hi * 8;
        bf16x8 va[8];
#pragma unroll
        for (int ct = 0; ct < 4; ct++) {
            va[2 * ct]     = *(const bf16x8*)(vp + (size_t)ct * 16 * SEQ);
            va[2 * ct + 1] = *(const bf16x8*)(vp + (size_t)ct * 16 * SEQ + 32);
        }
        // ---- P^T B-frags back from LDS (same wave, DS in-order)
        bf16x8 pb0[4], pb1[4];
#pragma unroll
        for (int nq = 0; nq < 4; nq++) {
            pb0[nq] = *(const bf16x8*)(PBw + (nq * 16 + lo) * 64 + (hi ^ lx) * 8);
            pb1[nq] = *(const bf16x8*)(PBw + (nq * 16 + lo) * 64 + ((4 + hi) ^ lx) * 8);
        }
        // ---- O^T += V^T·P^T
#pragma unroll
        for (int ct = 0; ct < 4; ct++)
#pragma unroll
            for (int nq = 0; nq < 4; nq++) {
                o[ct][nq] = __builtin_amdgcn_mfma_f32_16x16x32_bf16(va[2 * ct], pb0[nq], o[ct][nq], 0, 0, 0);
                o[ct][nq] = __builtin_amdgcn_mfma_f32_16x16x32_bf16(va[2 * ct + 1], pb1[nq], o[ct][nq], 0, 0, 0);
            }
    }
    // ---- l reduction + store
#pragma unroll
    for (int nq = 0; nq < 4; nq++) {
        l4[nq] += __shfl_xor(l4[nq], 16, 64);
        l4[nq] += __shfl_xor(l4[nq], 32, 64);
    }
    if (hi == 0) {
        float* lb = lpart + (size_t)(bm * 36 + pidx) * 256 + w * 64;
#pragma unroll
        for (int nq = 0; nq < 4; nq++) lb[nq * 16 + lo] = l4[nq];
    }
    // ---- O partial: wave-private LDS transpose -> dense bf16 [q][c] stores
#pragma unroll
    for (int ct = 0; ct < 4; ct++)
#pragma unroll
        for (int nq = 0; nq < 4; nq++) {
            bf16x4 ov;
#pragma unroll
            for (int r = 0; r < 4; r++) ov[r] = (bf16_t)o[ct][nq][r];
            *(bf16x4*)(PBw + (nq * 16 + lo) * 64 +
                       (((2 * ct + (hi >> 1)) ^ lx) * 8) + (hi & 1) * 4) = ov;
        }
    bf16_t* Ob = Opart + (size_t)(bm * 36 + pidx) * 16384 + (size_t)w * 4096;
#pragma unroll
    for (int i = 0; i < 8; i++) {
        int row = i * 8 + (lane >> 3);
        int j   = lane & 7;
        bf16x8 v = *(const bf16x8*)(PBw + row * 64 + ((j ^ (row & 7)) * 8));
        *(bf16x8*)(Ob + (size_t)row * 64 + j * 8) = v;
    }
}

// ---------------------------------------------------------------------------
// merge v4: XCD-remapped, one bf16x8 chunk per thread, dense. (unchanged)
// ---------------------------------------------------------------------------
__global__ __launch_bounds__(256) void va_merge(const bf16_t* __restrict__ Opart,
                                                const float* __restrict__ lpart,
                                                bf16_t* __restrict__ yob) {
    int idx = blockIdx.x;                   // [0,1536)
    int g = idx >> 3;                       // [0,192)
    int bm = (idx & 7) + 8 * (g >> 6);      // same-bm -> same XCD as attn
    int inner = g & 63;
    int rem = inner * 256 + threadIdx.x;    // [0,16384) chunk within bm
    int f    = rem >> 11;
    int rem2 = rem & 2047;
    int q    = rem2 >> 3;
    int c8   = rem2 & 7;
    int sbase = bm * 36 + f * (f + 1) / 2;

    float lsum = 0.f;
    for (int kf = 0; kf <= f; kf++)
        lsum += lpart[(size_t)(sbase + kf) * 256 + q];

    float v[8] = {0.f, 0.f, 0.f, 0.f, 0.f, 0.f, 0.f, 0.f};
    const bf16_t* Ob = Opart + (size_t)sbase * 16384 + (size_t)q * 64 + c8 * 8;
    for (int kf = 0; kf <= f; kf++) {
        bf16x8 pv = *(const bf16x8*)(Ob + (size_t)kf * 16384);
#pragma unroll
        for (int r = 0; r < 8; r++) v[r] += (float)pv[r];
    }

    float invl = 1.0f / lsum;
    int head = bm % 12, b = bm / 12;
    bf16x8 o8;
#pragma unroll
    for (int r = 0; r < 8; r++) o8[r] = (bf16_t)(v[r] * invl);
    *(bf16x8*)(yob + (size_t)(b * 8 + f) * NSTRIDE + (size_t)q * 768 + head * 64 + c8 * 8) = o8;
}

// ---------------------------------------------------------------------------
// Proj GEMM via MFMA + mp_sum. XCD-remapped by n.
// v3: 384 blocks (64x128 tile, 4 waves x 64x32) — keeps the occupancy fix
// from v2 (192 blocks left a quarter of the chip idle), drops the register
// prefetch (proven neutral on qkv). Plain in-step loads.
// ---------------------------------------------------------------------------
__global__ __launch_bounds__(256, 2) void va_proj_mfma(const bf16_t* __restrict__ Wb,
                                                       const bf16_t* __restrict__ yob,
                                                       const float* __restrict__ x,
                                                       float* __restrict__ out) {
    int idx = blockIdx.x;                   // [0,384)
    int n  = (idx & 7) + 8 * ((idx >> 3) & 1);
    int rest = idx >> 4;                    // [0,24)
    int p0 = (rest & 1) * 128;
    int m0 = (rest >> 1) * 64;              // [0,12)*64
    int tid = threadIdx.x;
    int lane = tid & 63, w = tid >> 6;      // w = column-slice index [0,4)
    int lo = lane & 15, hi = lane >> 4;

    const bf16_t* Ap = Wb + (size_t)(m0 + lo) * 768 + hi * 8;
    const bf16_t* Bp = yob + (size_t)n * NSTRIDE + (size_t)(p0 + w * 32 + lo) * 768 + hi * 8;

    f32x4 acc[4][2];
#pragma unroll
    for (int mt = 0; mt < 4; mt++)
#pragma unroll
        for (int nt = 0; nt < 2; nt++) acc[mt][nt] = (f32x4){0.f, 0.f, 0.f, 0.f};

    for (int k0 = 0; k0 < 768; k0 += 32) {
        bf16x8 af[4], bfr[2];
#pragma unroll
        for (int mt = 0; mt < 4; mt++)
            af[mt] = *(const bf16x8*)(Ap + (size_t)mt * 16 * 768 + k0);
#pragma unroll
        for (int nt = 0; nt < 2; nt++)
            bfr[nt] = *(const bf16x8*)(Bp + (size_t)nt * 16 * 768 + k0);
#pragma unroll
        for (int mt = 0; mt < 4; mt++)
#pragma unroll
            for (int nt = 0; nt < 2; nt++)
                acc[mt][nt] = __builtin_amdgcn_mfma_f32_16x16x32_bf16(af[mt], bfr[nt], acc[mt][nt], 0, 0, 0);
    }

    const float* xn = x + (size_t)n * NSTRIDE;
    float* on = out + (size_t)n * NSTRIDE;
#pragma unroll
    for (int mt = 0; mt < 4; mt++)
#pragma unroll
        for (int nt = 0; nt < 2; nt++)
#pragma unroll
            for (int r = 0; r < 4; r++) {
                int oo = m0 + mt * 16 + hi * 4 + r;
                int p  = p0 + w * 32 + nt * 16 + lo;
                size_t idx2 = (size_t)oo * 256 + p;
                on[idx2] = (xn[idx2] * 0.7f + acc[mt][nt][r] * 0.3f) * 1.3130643f;
            }
}

// ---------------------------------------------------------------------------
extern "C" void kernel_launch(void* const* d_in, const int* in_sizes, int n_in,
                              void* d_out, int out_size, void* d_ws, size_t ws_size,
                              hipStream_t stream) {
    const float* x     = (const float*)d_in[0];
    const float* wqkv  = (const float*)d_in[1];
    const float* wproj = (const float*)d_in[2];
    float* out = (float*)d_out;

    bf16_t* Opart = (bf16_t*)d_ws;                             // 24*36*16384 bf16
    float*  lpart = (float*)(Opart + (size_t)24 * 36 * 16384); // 24*36*256 fp32
    bf16_t* wqkv_nb  = (bf16_t*)(lpart + (size_t)24 * 36 * 256);
    bf16_t* xt       = wqkv_nb + (size_t)3072 * 768;
    bf16_t* qkvb     = xt + NSTRIDE * 16;
    bf16_t* yob      = qkvb + 3 * QKV_ONE;

    va_prep<<<6144, 256, 0, stream>>>(wqkv, wproj, x, wqkv_nb, xt);
    va_qkv_mfma<<<576, 256, 0, stream>>>(wqkv_nb, xt, qkvb);
    va_attn<<<864, 256, 0, stream>>>(qkvb, Opart, lpart);
    va_merge<<<1536, 256, 0, stream>>>(Opart, lpart, yob);
    va_proj_mfma<<<384, 256, 0, stream>>>(wqkv_nb + (size_t)2304 * 768, yob, x, out);
}

// Round 3
// 200.152 us; speedup vs baseline: 1.2761x; 1.0271x over previous
//
#include <hip/hip_runtime.h>

typedef __bf16 bf16_t;
typedef __bf16 bf16x4 __attribute__((ext_vector_type(4)));
typedef __bf16 bf16x8 __attribute__((ext_vector_type(8)));
typedef float  f32x4  __attribute__((ext_vector_type(4)));

// Problem constants (setup_inputs: b=2, t=8, C=768, h=w=16)
static constexpr int NHEADS = 12, HC = 64, HW = 256, SEQ = 2048;
static constexpr size_t QKV_ONE = (size_t)2 * NHEADS * SEQ * HC;   // 3145728 elems per q/k/v slab
static constexpr size_t NSTRIDE = 768 * 256;                        // 196608

// ---------------------------------------------------------------------------
// prep: blocks 0..3071 = mp_weight rows (wqkv then wproj, proj columns
// permuted to j=head*64+c); blocks 3072..6143 = x fp32->bf16 transpose tiles.
// ---------------------------------------------------------------------------
__global__ __launch_bounds__(256) void va_prep(const float* __restrict__ wqkv,
                                               const float* __restrict__ wproj,
                                               const float* __restrict__ x,
                                               bf16_t* __restrict__ wout,
                                               bf16_t* __restrict__ xt) {
    int blk = blockIdx.x;
    if (blk < 3072) {
        int row = blk;
        bool is_proj = (row >= 2304);
        const float* wr = is_proj ? wproj + (size_t)(row - 2304) * 768
                                  : wqkv + (size_t)row * 768;
        float part = 0.f;
        for (int i = threadIdx.x; i < 768; i += 256) { float v = wr[i]; part += v * v; }
#pragma unroll
        for (int off = 32; off > 0; off >>= 1) part += __shfl_down(part, off, 64);
        __shared__ float red[4];
        if ((threadIdx.x & 63) == 0) red[threadIdx.x >> 6] = part;
        __syncthreads();
        if (threadIdx.x == 0) {
            float s = red[0] + red[1] + red[2] + red[3];
            red[0] = 1.0f / (2.7712813e-3f + sqrtf(s));   // EPS*sqrt(768) + ||w||
        }
        __syncthreads();
        float sc = red[0];
        for (int i = threadIdx.x; i < 768; i += 256) {
            int j = is_proj ? ((i % 12) * 64 + i / 12) : i;
            wout[(size_t)row * 768 + j] = (bf16_t)(wr[i] * sc);
        }
    } else {
        int t = blk - 3072;                 // [0, 3072)
        int n  = t & 15;
        int rest = t >> 4;                  // [0,192)
        int p0 = (rest & 7) * 32;
        int c0 = (rest >> 3) * 32;          // [0,24) * 32
        __shared__ float sm[32][33];
        int tx = threadIdx.x & 31, ty = threadIdx.x >> 5;
        const float* xp = x + (size_t)n * NSTRIDE;
#pragma unroll
        for (int i = 0; i < 4; i++)
            sm[ty + i * 8][tx] = xp[(size_t)(c0 + ty + i * 8) * 256 + p0 + tx];
        __syncthreads();
        bf16_t* xo = xt + (size_t)n * NSTRIDE;
#pragma unroll
        for (int i = 0; i < 4; i++)
            xo[(size_t)(p0 + ty + i * 8) * 768 + c0 + tx] = (bf16_t)sm[tx][ty + i * 8];
    }
}

// ---------------------------------------------------------------------------
// QKV GEMM via MFMA, RoPE + q-scale fused. XCD-remapped by n.
// v3: LDS-staged (m97-family) — verified round 2 (qkv dropped out of top-5).
// ---------------------------------------------------------------------------
__global__ __launch_bounds__(256, 2) void va_qkv_mfma(const bf16_t* __restrict__ Wb,
                                                      const bf16_t* __restrict__ xt,
                                                      bf16_t* __restrict__ qkvb) {
    int idx = blockIdx.x;                   // [0,576)
    int n  = (idx & 7) + 8 * ((idx >> 3) & 1);
    int rest = idx >> 4;                    // [0,36)
    int p0 = (rest & 1) * 128;
    int m0 = (rest >> 1) * 128;             // [0,18)*128
    int tid = threadIdx.x;
    int lane = tid & 63, w = tid >> 6;
    int lo = lane & 15, hi = lane >> 4;
    int wm = w >> 1, wn = w & 1;
    int lx = lo & 7;                        // read-side swizzle key (= row&7)

    __shared__ bf16_t Asm[128 * 64];        // [row 0..127][k 0..63], 128B rows
    __shared__ bf16_t Bsm[128 * 64];

    // staging: thread t owns rows (t>>3)+32i, 16B chunk c=(t&7); dest chunk
    // is XOR-swizzled by row&7 (invariant under +32).
    int srow = tid >> 3, schunk = tid & 7;
    const bf16_t* Ag = Wb + (size_t)(m0 + srow) * 768 + schunk * 8;
    const bf16_t* Bg = xt + (size_t)n * NSTRIDE + (size_t)(p0 + srow) * 768 + schunk * 8;
    int sdst = srow * 128 + ((schunk ^ (srow & 7)) << 4);

    f32x4 acc[4][4];
#pragma unroll
    for (int mt = 0; mt < 4; mt++)
#pragma unroll
        for (int nt = 0; nt < 4; nt++) acc[mt][nt] = (f32x4){0.f, 0.f, 0.f, 0.f};

    bf16x8 sa[4], sb[4];                    // stage registers (4 rows each of A,B)

    auto gload = [&](int k0) {
#pragma unroll
        for (int i = 0; i < 4; i++) {
            sa[i] = *(const bf16x8*)(Ag + (size_t)i * 32 * 768 + k0);
            sb[i] = *(const bf16x8*)(Bg + (size_t)i * 32 * 768 + k0);
        }
    };
    auto swrite = [&]() {
        char* Ac = (char*)Asm;
        char* Bc = (char*)Bsm;
#pragma unroll
        for (int i = 0; i < 4; i++) {
            *(bf16x8*)(Ac + sdst + i * 32 * 128) = sa[i];
            *(bf16x8*)(Bc + sdst + i * 32 * 128) = sb[i];
        }
    };

    gload(0);
    for (int s = 0; s < 12; s++) {
        __syncthreads();                    // previous tile's ds_reads complete
        swrite();                           // (compiler waits vmcnt for sa/sb)
        if (s < 11) gload((s + 1) * 64);    // issue next tile early; drains
                                            // under this tile's MFMA
        __syncthreads();                    // tile visible
#pragma unroll
        for (int kk = 0; kk < 64; kk += 32) {
            int cb = kk >> 3;               // chunk base: 0 or 4
            bf16x8 af[4], bfr[4];
            const char* Ac = (const char*)Asm;
            const char* Bc = (const char*)Bsm;
#pragma unroll
            for (int mt = 0; mt < 4; mt++) {
                int row = wm * 64 + mt * 16 + lo;
                af[mt] = *(const bf16x8*)(Ac + row * 128 + (((cb + hi) ^ lx) << 4));
            }
#pragma unroll
            for (int nt = 0; nt < 4; nt++) {
                int row = wn * 64 + nt * 16 + lo;
                bfr[nt] = *(const bf16x8*)(Bc + row * 128 + (((cb + hi) ^ lx) << 4));
            }
#pragma unroll
            for (int mt = 0; mt < 4; mt++)
#pragma unroll
                for (int nt = 0; nt < 4; nt++)
                    acc[mt][nt] = __builtin_amdgcn_mfma_f32_16x16x32_bf16(af[mt], bfr[nt], acc[mt][nt], 0, 0, 0);
        }
    }

    int head_global = (m0 + wm * 64) >> 6;
    int qkv_idx = head_global / 12;
    int head    = head_global % 12;
    int b = n >> 3, tt = n & 7;
    int bm = b * 12 + head;
    if (qkv_idx < 2) {
        float qsc = (qkv_idx == 0) ? 0.125f : 1.0f;
        float ttf = (float)tt;
#pragma unroll
        for (int mt = 0; mt < 2; mt++)
#pragma unroll
            for (int r = 0; r < 4; r++) {
                int j = mt * 16 + hi * 4 + r;
                float ang = ttf * __expf(-(float)j * 0.2878231366242557f);
                float cs = __cosf(ang), sn = __sinf(ang);
#pragma unroll
                for (int nt = 0; nt < 4; nt++) {
                    float x1 = acc[mt][nt][r], x2 = acc[mt + 2][nt][r];
                    acc[mt][nt][r]     = (x1 * cs - x2 * sn) * qsc;
                    acc[mt + 2][nt][r] = (x1 * sn + x2 * cs) * qsc;
                }
            }
        bf16_t* dst = qkvb + (size_t)qkv_idx * QKV_ONE + ((size_t)bm * SEQ + (size_t)tt * HW) * HC;
#pragma unroll
        for (int mt = 0; mt < 4; mt++)
#pragma unroll
            for (int nt = 0; nt < 4; nt++)
#pragma unroll
                for (int r = 0; r < 4; r++) {
                    int cc = mt * 16 + hi * 4 + r;
                    int p  = p0 + wn * 64 + nt * 16 + lo;
                    dst[(size_t)p * HC + cc] = (bf16_t)acc[mt][nt][r];
                }
    } else {
        bf16_t* dst = qkvb + 2 * QKV_ONE + (size_t)bm * HC * SEQ + (size_t)tt * HW;
#pragma unroll
        for (int mt = 0; mt < 4; mt++)
#pragma unroll
            for (int nt = 0; nt < 4; nt++)
#pragma unroll
                for (int r = 0; r < 4; r++) {
                    int cc = mt * 16 + hi * 4 + r;
                    int p  = p0 + wn * 64 + nt * 16 + lo;
                    dst[(size_t)cc * SEQ + p] = (bf16_t)acc[mt][nt][r];
                }
    }
}

// ---------------------------------------------------------------------------
// MFMA flash attention v9: ONLINE. One wave (64-thread block) owns 64 queries
// of (bm, frame f) and iterates ALL keys kpos in [0, (f+1)*256), accumulating
// O in fp32 regs and l in regs (exp without max-subtraction, same math as the
// partial+merge scheme which only divided by sum(l) at the end). Kills the
// 28 MB Opart write (measured 91.5 MB after L2 amplification) + 28 MB merge
// re-read: va_merge is GONE; this kernel normalizes and writes yob directly.
// Inner kt-step body is byte-identical to the verified v8 kernel.
// Balance: work ~ (f+1). 768 blocks; tasks sorted f-descending (index s) and
// striped so the triples {u, u+256, u+512} landing on the same CU (round-
// robin dispatch model) mix heavy+mid+light. bm == blk (mod 8) keeps each
// bm's 512 KB K/V pinned to one XCD's L2.
// ---------------------------------------------------------------------------
__global__ __launch_bounds__(64) void va_attn(const bf16_t* __restrict__ qkvb,
                                              bf16_t* __restrict__ yob) {
    int blk = blockIdx.x;                   // [0,768)
    int u = blk & 255, v = blk >> 8;        // CU-slot stripe / round
    int s = v * 256 + u;                    // f-descending task index
    int f = 7 - (s / 96);
    int within = s % 96;
    int bm = within % 24;                   // == blk % 24 -> bm%8 == blk%8
    int qs = within / 24;                   // [0,4) 64-query subtile of frame

    int lane = threadIdx.x;                 // single wave
    int lo = lane & 15, hi = lane >> 4;
    int lx = lo & 7;                        // swizzle key

    const bf16_t* qbase = qkvb + (size_t)bm * SEQ * HC;
    const bf16_t* kbase = qkvb + QKV_ONE + (size_t)bm * SEQ * HC;
    const bf16_t* vbase = qkvb + 2 * QKV_ONE + (size_t)bm * HC * SEQ;

    __shared__ bf16_t PBw[64 * 64];         // wave-private P^T / O transpose

    // Q B-frags: queries f*256 + qs*64 .. +63 (q pre-scaled 0.125)
    const bf16_t* qrow = qbase + (size_t)(f * 256 + qs * 64 + lo) * HC;
    bf16x8 qf[4][2];
#pragma unroll
    for (int nq = 0; nq < 4; nq++) {
        qf[nq][0] = *(const bf16x8*)(qrow + (size_t)nq * 16 * HC + hi * 8);
        qf[nq][1] = *(const bf16x8*)(qrow + (size_t)nq * 16 * HC + 32 + hi * 8);
    }
    f32x4 o[4][4];
#pragma unroll
    for (int ct = 0; ct < 4; ct++)
#pragma unroll
        for (int nq = 0; nq < 4; nq++) o[ct][nq] = (f32x4){0.f, 0.f, 0.f, 0.f};
    float l4[4] = {0.f, 0.f, 0.f, 0.f};

    int kend = (f + 1) * 256;
    for (int kpos = 0; kpos < kend; kpos += 64) {
        // ---- K fragments direct from global (wave covers full 64B sectors)
        const bf16_t* kp = kbase + (size_t)(kpos + lo) * HC + hi * 8;
        bf16x8 ka[8];
#pragma unroll
        for (int mt = 0; mt < 4; mt++) {
            ka[2 * mt]     = *(const bf16x8*)(kp + (size_t)mt * 16 * HC);
            ka[2 * mt + 1] = *(const bf16x8*)(kp + (size_t)mt * 16 * HC + 32);
        }
        // ---- S^T = K·Q^T, exp, P^T -> wave-private LDS
#pragma unroll
        for (int mt = 0; mt < 4; mt++) {
#pragma unroll
            for (int nq = 0; nq < 4; nq++) {
                f32x4 sacc = (f32x4){0.f, 0.f, 0.f, 0.f};
                sacc = __builtin_amdgcn_mfma_f32_16x16x32_bf16(ka[2 * mt], qf[nq][0], sacc, 0, 0, 0);
                sacc = __builtin_amdgcn_mfma_f32_16x16x32_bf16(ka[2 * mt + 1], qf[nq][1], sacc, 0, 0, 0);
                bf16x4 pk;
#pragma unroll
                for (int r = 0; r < 4; r++) {
                    float p = __expf(sacc[r]);
                    l4[nq] += p;
                    pk[r] = (bf16_t)p;
                }
                *(bf16x4*)(PBw + (nq * 16 + lo) * 64 +
                           (((2 * mt + (hi >> 1)) ^ lx) * 8) + (hi & 1) * 4) = pk;
            }
        }
        // ---- V fragments direct from global (transposed slab)
        const bf16_t* vp = vbase + (size_t)(lo) * SEQ + kpos + hi * 8;
        bf16x8 va[8];
#pragma unroll
        for (int ct = 0; ct < 4; ct++) {
            va[2 * ct]     = *(const bf16x8*)(vp + (size_t)ct * 16 * SEQ);
            va[2 * ct + 1] = *(const bf16x8*)(vp + (size_t)ct * 16 * SEQ + 32);
        }
        // ---- P^T B-frags back from LDS (same wave, DS in-order)
        bf16x8 pb0[4], pb1[4];
#pragma unroll
        for (int nq = 0; nq < 4; nq++) {
            pb0[nq] = *(const bf16x8*)(PBw + (nq * 16 + lo) * 64 + (hi ^ lx) * 8);
            pb1[nq] = *(const bf16x8*)(PBw + (nq * 16 + lo) * 64 + ((4 + hi) ^ lx) * 8);
        }
        // ---- O^T += V^T·P^T
#pragma unroll
        for (int ct = 0; ct < 4; ct++)
#pragma unroll
            for (int nq = 0; nq < 4; nq++) {
                o[ct][nq] = __builtin_amdgcn_mfma_f32_16x16x32_bf16(va[2 * ct], pb0[nq], o[ct][nq], 0, 0, 0);
                o[ct][nq] = __builtin_amdgcn_mfma_f32_16x16x32_bf16(va[2 * ct + 1], pb1[nq], o[ct][nq], 0, 0, 0);
            }
    }
    // ---- l reduction (butterfly over hi): every lane gets l of query nq*16+lo
    float invl[4];
#pragma unroll
    for (int nq = 0; nq < 4; nq++) {
        l4[nq] += __shfl_xor(l4[nq], 16, 64);
        l4[nq] += __shfl_xor(l4[nq], 32, 64);
        invl[nq] = 1.0f / l4[nq];
    }
    // ---- O normalize + wave-private LDS transpose -> dense bf16 yob stores
#pragma unroll
    for (int ct = 0; ct < 4; ct++)
#pragma unroll
        for (int nq = 0; nq < 4; nq++) {
            bf16x4 ov;
#pragma unroll
            for (int r = 0; r < 4; r++) ov[r] = (bf16_t)(o[ct][nq][r] * invl[nq]);
            *(bf16x4*)(PBw + (nq * 16 + lo) * 64 +
                       (((2 * ct + (hi >> 1)) ^ lx) * 8) + (hi & 1) * 4) = ov;
        }
    int head = bm % 12, b = bm / 12;
    bf16_t* yb = yob + (size_t)(b * 8 + f) * NSTRIDE + (size_t)(qs * 64) * 768 + head * 64;
#pragma unroll
    for (int i = 0; i < 8; i++) {
        int row = i * 8 + (lane >> 3);      // local query [0,64)
        int j   = lane & 7;                 // 8-elem channel chunk
        bf16x8 vv = *(const bf16x8*)(PBw + row * 64 + ((j ^ (row & 7)) * 8));
        *(bf16x8*)(yb + (size_t)row * 768 + j * 8) = vv;
    }
}

// ---------------------------------------------------------------------------
// Proj GEMM via MFMA + mp_sum. XCD-remapped by n. (unchanged from round 2)
// ---------------------------------------------------------------------------
__global__ __launch_bounds__(256, 2) void va_proj_mfma(const bf16_t* __restrict__ Wb,
                                                       const bf16_t* __restrict__ yob,
                                                       const float* __restrict__ x,
                                                       float* __restrict__ out) {
    int idx = blockIdx.x;                   // [0,384)
    int n  = (idx & 7) + 8 * ((idx >> 3) & 1);
    int rest = idx >> 4;                    // [0,24)
    int p0 = (rest & 1) * 128;
    int m0 = (rest >> 1) * 64;              // [0,12)*64
    int tid = threadIdx.x;
    int lane = tid & 63, w = tid >> 6;      // w = column-slice index [0,4)
    int lo = lane & 15, hi = lane >> 4;

    const bf16_t* Ap = Wb + (size_t)(m0 + lo) * 768 + hi * 8;
    const bf16_t* Bp = yob + (size_t)n * NSTRIDE + (size_t)(p0 + w * 32 + lo) * 768 + hi * 8;

    f32x4 acc[4][2];
#pragma unroll
    for (int mt = 0; mt < 4; mt++)
#pragma unroll
        for (int nt = 0; nt < 2; nt++) acc[mt][nt] = (f32x4){0.f, 0.f, 0.f, 0.f};

    for (int k0 = 0; k0 < 768; k0 += 32) {
        bf16x8 af[4], bfr[2];
#pragma unroll
        for (int mt = 0; mt < 4; mt++)
            af[mt] = *(const bf16x8*)(Ap + (size_t)mt * 16 * 768 + k0);
#pragma unroll
        for (int nt = 0; nt < 2; nt++)
            bfr[nt] = *(const bf16x8*)(Bp + (size_t)nt * 16 * 768 + k0);
#pragma unroll
        for (int mt = 0; mt < 4; mt++)
#pragma unroll
            for (int nt = 0; nt < 2; nt++)
                acc[mt][nt] = __builtin_amdgcn_mfma_f32_16x16x32_bf16(af[mt], bfr[nt], acc[mt][nt], 0, 0, 0);
    }

    const float* xn = x + (size_t)n * NSTRIDE;
    float* on = out + (size_t)n * NSTRIDE;
#pragma unroll
    for (int mt = 0; mt < 4; mt++)
#pragma unroll
        for (int nt = 0; nt < 2; nt++)
#pragma unroll
            for (int r = 0; r < 4; r++) {
                int oo = m0 + mt * 16 + hi * 4 + r;
                int p  = p0 + w * 32 + nt * 16 + lo;
                size_t idx2 = (size_t)oo * 256 + p;
                on[idx2] = (xn[idx2] * 0.7f + acc[mt][nt][r] * 0.3f) * 1.3130643f;
            }
}

// ---------------------------------------------------------------------------
extern "C" void kernel_launch(void* const* d_in, const int* in_sizes, int n_in,
                              void* d_out, int out_size, void* d_ws, size_t ws_size,
                              hipStream_t stream) {
    const float* x     = (const float*)d_in[0];
    const float* wqkv  = (const float*)d_in[1];
    const float* wproj = (const float*)d_in[2];
    float* out = (float*)d_out;

    // Workspace layout kept identical to v8 (Opart/lpart slots now unused).
    bf16_t* Opart = (bf16_t*)d_ws;                             // (unused)
    float*  lpart = (float*)(Opart + (size_t)24 * 36 * 16384); // (unused)
    bf16_t* wqkv_nb  = (bf16_t*)(lpart + (size_t)24 * 36 * 256);
    bf16_t* xt       = wqkv_nb + (size_t)3072 * 768;
    bf16_t* qkvb     = xt + NSTRIDE * 16;
    bf16_t* yob      = qkvb + 3 * QKV_ONE;

    va_prep<<<6144, 256, 0, stream>>>(wqkv, wproj, x, wqkv_nb, xt);
    va_qkv_mfma<<<576, 256, 0, stream>>>(wqkv_nb, xt, qkvb);
    va_attn<<<768, 64, 0, stream>>>(qkvb, yob);
    va_proj_mfma<<<192 * 2, 256, 0, stream>>>(wqkv_nb + (size_t)2304 * 768, yob, x, out);
}

// Round 4
// 200.016 us; speedup vs baseline: 1.2770x; 1.0007x over previous
//
#include <hip/hip_runtime.h>

typedef __bf16 bf16_t;
typedef __bf16 bf16x4 __attribute__((ext_vector_type(4)));
typedef __bf16 bf16x8 __attribute__((ext_vector_type(8)));
typedef float  f32x4  __attribute__((ext_vector_type(4)));

// Problem constants (setup_inputs: b=2, t=8, C=768, h=w=16)
static constexpr int NHEADS = 12, HC = 64, HW = 256, SEQ = 2048;
static constexpr size_t QKV_ONE = (size_t)2 * NHEADS * SEQ * HC;   // 3145728 elems per q/k/v slab
static constexpr size_t NSTRIDE = 768 * 256;                        // 196608

// ---------------------------------------------------------------------------
// prep: blocks 0..3071 = mp_weight rows (wqkv then wproj, proj columns
// permuted to j=head*64+c); blocks 3072..6143 = x fp32->bf16 transpose tiles.
// ---------------------------------------------------------------------------
__global__ __launch_bounds__(256) void va_prep(const float* __restrict__ wqkv,
                                               const float* __restrict__ wproj,
                                               const float* __restrict__ x,
                                               bf16_t* __restrict__ wout,
                                               bf16_t* __restrict__ xt) {
    int blk = blockIdx.x;
    if (blk < 3072) {
        int row = blk;
        bool is_proj = (row >= 2304);
        const float* wr = is_proj ? wproj + (size_t)(row - 2304) * 768
                                  : wqkv + (size_t)row * 768;
        float part = 0.f;
        for (int i = threadIdx.x; i < 768; i += 256) { float v = wr[i]; part += v * v; }
#pragma unroll
        for (int off = 32; off > 0; off >>= 1) part += __shfl_down(part, off, 64);
        __shared__ float red[4];
        if ((threadIdx.x & 63) == 0) red[threadIdx.x >> 6] = part;
        __syncthreads();
        if (threadIdx.x == 0) {
            float s = red[0] + red[1] + red[2] + red[3];
            red[0] = 1.0f / (2.7712813e-3f + sqrtf(s));   // EPS*sqrt(768) + ||w||
        }
        __syncthreads();
        float sc = red[0];
        for (int i = threadIdx.x; i < 768; i += 256) {
            int j = is_proj ? ((i % 12) * 64 + i / 12) : i;
            wout[(size_t)row * 768 + j] = (bf16_t)(wr[i] * sc);
        }
    } else {
        int t = blk - 3072;                 // [0, 3072)
        int n  = t & 15;
        int rest = t >> 4;                  // [0,192)
        int p0 = (rest & 7) * 32;
        int c0 = (rest >> 3) * 32;          // [0,24) * 32
        __shared__ float sm[32][33];
        int tx = threadIdx.x & 31, ty = threadIdx.x >> 5;
        const float* xp = x + (size_t)n * NSTRIDE;
#pragma unroll
        for (int i = 0; i < 4; i++)
            sm[ty + i * 8][tx] = xp[(size_t)(c0 + ty + i * 8) * 256 + p0 + tx];
        __syncthreads();
        bf16_t* xo = xt + (size_t)n * NSTRIDE;
#pragma unroll
        for (int i = 0; i < 4; i++)
            xo[(size_t)(p0 + ty + i * 8) * 768 + c0 + tx] = (bf16_t)sm[tx][ty + i * 8];
    }
}

// ---------------------------------------------------------------------------
// QKV GEMM via MFMA, RoPE + q-scale fused. XCD-remapped by n.
// v3: LDS-staged (m97-family) — verified round 2 (qkv dropped out of top-5).
// ---------------------------------------------------------------------------
__global__ __launch_bounds__(256, 2) void va_qkv_mfma(const bf16_t* __restrict__ Wb,
                                                      const bf16_t* __restrict__ xt,
                                                      bf16_t* __restrict__ qkvb) {
    int idx = blockIdx.x;                   // [0,576)
    int n  = (idx & 7) + 8 * ((idx >> 3) & 1);
    int rest = idx >> 4;                    // [0,36)
    int p0 = (rest & 1) * 128;
    int m0 = (rest >> 1) * 128;             // [0,18)*128
    int tid = threadIdx.x;
    int lane = tid & 63, w = tid >> 6;
    int lo = lane & 15, hi = lane >> 4;
    int wm = w >> 1, wn = w & 1;
    int lx = lo & 7;                        // read-side swizzle key (= row&7)

    __shared__ bf16_t Asm[128 * 64];        // [row 0..127][k 0..63], 128B rows
    __shared__ bf16_t Bsm[128 * 64];

    // staging: thread t owns rows (t>>3)+32i, 16B chunk c=(t&7); dest chunk
    // is XOR-swizzled by row&7 (invariant under +32).
    int srow = tid >> 3, schunk = tid & 7;
    const bf16_t* Ag = Wb + (size_t)(m0 + srow) * 768 + schunk * 8;
    const bf16_t* Bg = xt + (size_t)n * NSTRIDE + (size_t)(p0 + srow) * 768 + schunk * 8;
    int sdst = srow * 128 + ((schunk ^ (srow & 7)) << 4);

    f32x4 acc[4][4];
#pragma unroll
    for (int mt = 0; mt < 4; mt++)
#pragma unroll
        for (int nt = 0; nt < 4; nt++) acc[mt][nt] = (f32x4){0.f, 0.f, 0.f, 0.f};

    bf16x8 sa[4], sb[4];                    // stage registers (4 rows each of A,B)

    auto gload = [&](int k0) {
#pragma unroll
        for (int i = 0; i < 4; i++) {
            sa[i] = *(const bf16x8*)(Ag + (size_t)i * 32 * 768 + k0);
            sb[i] = *(const bf16x8*)(Bg + (size_t)i * 32 * 768 + k0);
        }
    };
    auto swrite = [&]() {
        char* Ac = (char*)Asm;
        char* Bc = (char*)Bsm;
#pragma unroll
        for (int i = 0; i < 4; i++) {
            *(bf16x8*)(Ac + sdst + i * 32 * 128) = sa[i];
            *(bf16x8*)(Bc + sdst + i * 32 * 128) = sb[i];
        }
    };

    gload(0);
    for (int s = 0; s < 12; s++) {
        __syncthreads();                    // previous tile's ds_reads complete
        swrite();                           // (compiler waits vmcnt for sa/sb)
        if (s < 11) gload((s + 1) * 64);    // issue next tile early; drains
                                            // under this tile's MFMA
        __syncthreads();                    // tile visible
#pragma unroll
        for (int kk = 0; kk < 64; kk += 32) {
            int cb = kk >> 3;               // chunk base: 0 or 4
            bf16x8 af[4], bfr[4];
            const char* Ac = (const char*)Asm;
            const char* Bc = (const char*)Bsm;
#pragma unroll
            for (int mt = 0; mt < 4; mt++) {
                int row = wm * 64 + mt * 16 + lo;
                af[mt] = *(const bf16x8*)(Ac + row * 128 + (((cb + hi) ^ lx) << 4));
            }
#pragma unroll
            for (int nt = 0; nt < 4; nt++) {
                int row = wn * 64 + nt * 16 + lo;
                bfr[nt] = *(const bf16x8*)(Bc + row * 128 + (((cb + hi) ^ lx) << 4));
            }
#pragma unroll
            for (int mt = 0; mt < 4; mt++)
#pragma unroll
                for (int nt = 0; nt < 4; nt++)
                    acc[mt][nt] = __builtin_amdgcn_mfma_f32_16x16x32_bf16(af[mt], bfr[nt], acc[mt][nt], 0, 0, 0);
        }
    }

    int head_global = (m0 + wm * 64) >> 6;
    int qkv_idx = head_global / 12;
    int head    = head_global % 12;
    int b = n >> 3, tt = n & 7;
    int bm = b * 12 + head;
    if (qkv_idx < 2) {
        float qsc = (qkv_idx == 0) ? 0.125f : 1.0f;
        float ttf = (float)tt;
#pragma unroll
        for (int mt = 0; mt < 2; mt++)
#pragma unroll
            for (int r = 0; r < 4; r++) {
                int j = mt * 16 + hi * 4 + r;
                float ang = ttf * __expf(-(float)j * 0.2878231366242557f);
                float cs = __cosf(ang), sn = __sinf(ang);
#pragma unroll
                for (int nt = 0; nt < 4; nt++) {
                    float x1 = acc[mt][nt][r], x2 = acc[mt + 2][nt][r];
                    acc[mt][nt][r]     = (x1 * cs - x2 * sn) * qsc;
                    acc[mt + 2][nt][r] = (x1 * sn + x2 * cs) * qsc;
                }
            }
        bf16_t* dst = qkvb + (size_t)qkv_idx * QKV_ONE + ((size_t)bm * SEQ + (size_t)tt * HW) * HC;
#pragma unroll
        for (int mt = 0; mt < 4; mt++)
#pragma unroll
            for (int nt = 0; nt < 4; nt++)
#pragma unroll
                for (int r = 0; r < 4; r++) {
                    int cc = mt * 16 + hi * 4 + r;
                    int p  = p0 + wn * 64 + nt * 16 + lo;
                    dst[(size_t)p * HC + cc] = (bf16_t)acc[mt][nt][r];
                }
    } else {
        bf16_t* dst = qkvb + 2 * QKV_ONE + (size_t)bm * HC * SEQ + (size_t)tt * HW;
#pragma unroll
        for (int mt = 0; mt < 4; mt++)
#pragma unroll
            for (int nt = 0; nt < 4; nt++)
#pragma unroll
                for (int r = 0; r < 4; r++) {
                    int cc = mt * 16 + hi * 4 + r;
                    int p  = p0 + wn * 64 + nt * 16 + lo;
                    dst[(size_t)cc * SEQ + p] = (bf16_t)acc[mt][nt][r];
                }
    }
}

// ---------------------------------------------------------------------------
// MFMA flash attention v10: online + block-level kf split, LDS combine.
// v9 post-mortem: traffic fix landed (129->15.8 MB) but dur was flat at
// 65.7us — OccupancyPercent 4.7% (768 waves on 1024 SIMDs = 0.75/SIMD), so
// every latency in the ~4900cy-per-k-step chain was fully exposed.
// v10: block = (bm, f, qs), 4 waves; wave w covers interleaved key chunks
// kpos = w*64 + 256*i (exactly f+1 k-steps per wave, perfectly balanced
// within the block, all 4 waves sweep the same 256-key window together).
// Each wave packs UNNORMALIZED bf16 O into its wave-private PBF slab (same
// precision as verified v8, which wrote raw bf16 partials to HBM) + l into
// LDS; one barrier; block sums 4 slabs + 4 l's in fp32, normalizes, writes
// yob. 3072 waves = 3/SIMD; 33KB LDS -> 3 blocks/CU. Inner k-step body is
// byte-identical to v9. bm == blk (mod 8) XCD pinning preserved.
// ---------------------------------------------------------------------------
__global__ __launch_bounds__(256, 3) void va_attn(const bf16_t* __restrict__ qkvb,
                                                  bf16_t* __restrict__ yob) {
    int blk = blockIdx.x;                   // [0,768)
    int u = blk & 255, v = blk >> 8;        // CU-slot stripe / round
    int s = v * 256 + u;                    // f-descending task index
    int f = 7 - (s / 96);
    int within = s % 96;
    int bm = within % 24;                   // == blk % 24 -> bm%8 == blk%8
    int qs = within / 24;                   // [0,4) 64-query subtile of frame

    int tid = threadIdx.x;
    int w = tid >> 6, lane = tid & 63;      // w = kf-slice of this wave
    int lo = lane & 15, hi = lane >> 4;
    int lx = lo & 7;                        // swizzle key

    const bf16_t* qbase = qkvb + (size_t)bm * SEQ * HC;
    const bf16_t* kbase = qkvb + QKV_ONE + (size_t)bm * SEQ * HC;
    const bf16_t* vbase = qkvb + 2 * QKV_ONE + (size_t)bm * HC * SEQ;

    __shared__ bf16_t PBF[4][64 * 64];      // wave-private P^T / O-partial slabs
    __shared__ float  Lsm[4][64];           // per-wave l vectors
    bf16_t* PBw = PBF[w];

    // Q B-frags: queries f*256 + qs*64 .. +63 (q pre-scaled 0.125)
    const bf16_t* qrow = qbase + (size_t)(f * 256 + qs * 64 + lo) * HC;
    bf16x8 qf[4][2];
#pragma unroll
    for (int nq = 0; nq < 4; nq++) {
        qf[nq][0] = *(const bf16x8*)(qrow + (size_t)nq * 16 * HC + hi * 8);
        qf[nq][1] = *(const bf16x8*)(qrow + (size_t)nq * 16 * HC + 32 + hi * 8);
    }
    f32x4 o[4][4];
#pragma unroll
    for (int ct = 0; ct < 4; ct++)
#pragma unroll
        for (int nq = 0; nq < 4; nq++) o[ct][nq] = (f32x4){0.f, 0.f, 0.f, 0.f};
    float l4[4] = {0.f, 0.f, 0.f, 0.f};

    int kend = (f + 1) * 256;
    for (int kpos = w * 64; kpos < kend; kpos += 256) {
        // ---- K fragments direct from global (wave covers full 64B sectors)
        const bf16_t* kp = kbase + (size_t)(kpos + lo) * HC + hi * 8;
        bf16x8 ka[8];
#pragma unroll
        for (int mt = 0; mt < 4; mt++) {
            ka[2 * mt]     = *(const bf16x8*)(kp + (size_t)mt * 16 * HC);
            ka[2 * mt + 1] = *(const bf16x8*)(kp + (size_t)mt * 16 * HC + 32);
        }
        // ---- S^T = K·Q^T, exp, P^T -> wave-private LDS
#pragma unroll
        for (int mt = 0; mt < 4; mt++) {
#pragma unroll
            for (int nq = 0; nq < 4; nq++) {
                f32x4 sacc = (f32x4){0.f, 0.f, 0.f, 0.f};
                sacc = __builtin_amdgcn_mfma_f32_16x16x32_bf16(ka[2 * mt], qf[nq][0], sacc, 0, 0, 0);
                sacc = __builtin_amdgcn_mfma_f32_16x16x32_bf16(ka[2 * mt + 1], qf[nq][1], sacc, 0, 0, 0);
                bf16x4 pk;
#pragma unroll
                for (int r = 0; r < 4; r++) {
                    float p = __expf(sacc[r]);
                    l4[nq] += p;
                    pk[r] = (bf16_t)p;
                }
                *(bf16x4*)(PBw + (nq * 16 + lo) * 64 +
                           (((2 * mt + (hi >> 1)) ^ lx) * 8) + (hi & 1) * 4) = pk;
            }
        }
        // ---- V fragments direct from global (transposed slab)
        const bf16_t* vp = vbase + (size_t)(lo) * SEQ + kpos + hi * 8;
        bf16x8 va[8];
#pragma unroll
        for (int ct = 0; ct < 4; ct++) {
            va[2 * ct]     = *(const bf16x8*)(vp + (size_t)ct * 16 * SEQ);
            va[2 * ct + 1] = *(const bf16x8*)(vp + (size_t)ct * 16 * SEQ + 32);
        }
        // ---- P^T B-frags back from LDS (same wave, DS in-order)
        bf16x8 pb0[4], pb1[4];
#pragma unroll
        for (int nq = 0; nq < 4; nq++) {
            pb0[nq] = *(const bf16x8*)(PBw + (nq * 16 + lo) * 64 + (hi ^ lx) * 8);
            pb1[nq] = *(const bf16x8*)(PBw + (nq * 16 + lo) * 64 + ((4 + hi) ^ lx) * 8);
        }
        // ---- O^T += V^T·P^T
#pragma unroll
        for (int ct = 0; ct < 4; ct++)
#pragma unroll
            for (int nq = 0; nq < 4; nq++) {
                o[ct][nq] = __builtin_amdgcn_mfma_f32_16x16x32_bf16(va[2 * ct], pb0[nq], o[ct][nq], 0, 0, 0);
                o[ct][nq] = __builtin_amdgcn_mfma_f32_16x16x32_bf16(va[2 * ct + 1], pb1[nq], o[ct][nq], 0, 0, 0);
            }
    }
    // ---- per-wave l reduction (butterfly over hi) + store to LDS
#pragma unroll
    for (int nq = 0; nq < 4; nq++) {
        l4[nq] += __shfl_xor(l4[nq], 16, 64);
        l4[nq] += __shfl_xor(l4[nq], 32, 64);
    }
    if (hi == 0) {
#pragma unroll
        for (int nq = 0; nq < 4; nq++) Lsm[w][nq * 16 + lo] = l4[nq];
    }
    // ---- pack UNNORMALIZED O-partial (bf16) into wave-private slab
#pragma unroll
    for (int ct = 0; ct < 4; ct++)
#pragma unroll
        for (int nq = 0; nq < 4; nq++) {
            bf16x4 ov;
#pragma unroll
            for (int r = 0; r < 4; r++) ov[r] = (bf16_t)o[ct][nq][r];
            *(bf16x4*)(PBw + (nq * 16 + lo) * 64 +
                       (((2 * ct + (hi >> 1)) ^ lx) * 8) + (hi & 1) * 4) = ov;
        }
    __syncthreads();
    // ---- combine 4 slabs + 4 l's in fp32, normalize, store yob
    int head = bm % 12, b = bm / 12;
    bf16_t* yb = yob + (size_t)(b * 8 + f) * NSTRIDE + (size_t)(qs * 64) * 768 + head * 64;
#pragma unroll
    for (int i = 0; i < 2; i++) {
        int c = i * 256 + tid;              // [0,512) chunk: 64 rows x 8 chunks
        int row = c >> 3, j = c & 7;
        int off = row * 64 + ((j ^ (row & 7)) * 8);
        float invl = 1.0f / (Lsm[0][row] + Lsm[1][row] + Lsm[2][row] + Lsm[3][row]);
        bf16x8 p0 = *(const bf16x8*)(PBF[0] + off);
        bf16x8 p1 = *(const bf16x8*)(PBF[1] + off);
        bf16x8 p2 = *(const bf16x8*)(PBF[2] + off);
        bf16x8 p3 = *(const bf16x8*)(PBF[3] + off);
        bf16x8 o8;
#pragma unroll
        for (int r = 0; r < 8; r++)
            o8[r] = (bf16_t)(((float)p0[r] + (float)p1[r] + (float)p2[r] + (float)p3[r]) * invl);
        *(bf16x8*)(yb + (size_t)row * 768 + j * 8) = o8;
    }
}

// ---------------------------------------------------------------------------
// Proj GEMM via MFMA + mp_sum. XCD-remapped by n. (unchanged)
// ---------------------------------------------------------------------------
__global__ __launch_bounds__(256, 2) void va_proj_mfma(const bf16_t* __restrict__ Wb,
                                                       const bf16_t* __restrict__ yob,
                                                       const float* __restrict__ x,
                                                       float* __restrict__ out) {
    int idx = blockIdx.x;                   // [0,384)
    int n  = (idx & 7) + 8 * ((idx >> 3) & 1);
    int rest = idx >> 4;                    // [0,24)
    int p0 = (rest & 1) * 128;
    int m0 = (rest >> 1) * 64;              // [0,12)*64
    int tid = threadIdx.x;
    int lane = tid & 63, w = tid >> 6;      // w = column-slice index [0,4)
    int lo = lane & 15, hi = lane >> 4;

    const bf16_t* Ap = Wb + (size_t)(m0 + lo) * 768 + hi * 8;
    const bf16_t* Bp = yob + (size_t)n * NSTRIDE + (size_t)(p0 + w * 32 + lo) * 768 + hi * 8;

    f32x4 acc[4][2];
#pragma unroll
    for (int mt = 0; mt < 4; mt++)
#pragma unroll
        for (int nt = 0; nt < 2; nt++) acc[mt][nt] = (f32x4){0.f, 0.f, 0.f, 0.f};

    for (int k0 = 0; k0 < 768; k0 += 32) {
        bf16x8 af[4], bfr[2];
#pragma unroll
        for (int mt = 0; mt < 4; mt++)
            af[mt] = *(const bf16x8*)(Ap + (size_t)mt * 16 * 768 + k0);
#pragma unroll
        for (int nt = 0; nt < 2; nt++)
            bfr[nt] = *(const bf16x8*)(Bp + (size_t)nt * 16 * 768 + k0);
#pragma unroll
        for (int mt = 0; mt < 4; mt++)
#pragma unroll
            for (int nt = 0; nt < 2; nt++)
                acc[mt][nt] = __builtin_amdgcn_mfma_f32_16x16x32_bf16(af[mt], bfr[nt], acc[mt][nt], 0, 0, 0);
    }

    const float* xn = x + (size_t)n * NSTRIDE;
    float* on = out + (size_t)n * NSTRIDE;
#pragma unroll
    for (int mt = 0; mt < 4; mt++)
#pragma unroll
        for (int nt = 0; nt < 2; nt++)
#pragma unroll
            for (int r = 0; r < 4; r++) {
                int oo = m0 + mt * 16 + hi * 4 + r;
                int p  = p0 + w * 32 + nt * 16 + lo;
                size_t idx2 = (size_t)oo * 256 + p;
                on[idx2] = (xn[idx2] * 0.7f + acc[mt][nt][r] * 0.3f) * 1.3130643f;
            }
}

// ---------------------------------------------------------------------------
extern "C" void kernel_launch(void* const* d_in, const int* in_sizes, int n_in,
                              void* d_out, int out_size, void* d_ws, size_t ws_size,
                              hipStream_t stream) {
    const float* x     = (const float*)d_in[0];
    const float* wqkv  = (const float*)d_in[1];
    const float* wproj = (const float*)d_in[2];
    float* out = (float*)d_out;

    // Workspace layout kept identical to v8 (Opart/lpart slots now unused).
    bf16_t* Opart = (bf16_t*)d_ws;                             // (unused)
    float*  lpart = (float*)(Opart + (size_t)24 * 36 * 16384); // (unused)
    bf16_t* wqkv_nb  = (bf16_t*)(lpart + (size_t)24 * 36 * 256);
    bf16_t* xt       = wqkv_nb + (size_t)3072 * 768;
    bf16_t* qkvb     = xt + NSTRIDE * 16;
    bf16_t* yob      = qkvb + 3 * QKV_ONE;

    va_prep<<<6144, 256, 0, stream>>>(wqkv, wproj, x, wqkv_nb, xt);
    va_qkv_mfma<<<576, 256, 0, stream>>>(wqkv_nb, xt, qkvb);
    va_attn<<<768, 256, 0, stream>>>(qkvb, yob);
    va_proj_mfma<<<384, 256, 0, stream>>>(wqkv_nb + (size_t)2304 * 768, yob, x, out);
}

// Round 5
// 171.245 us; speedup vs baseline: 1.4915x; 1.1680x over previous
//
#include <hip/hip_runtime.h>

typedef __bf16 bf16_t;
typedef __bf16 bf16x4 __attribute__((ext_vector_type(4)));
typedef __bf16 bf16x8 __attribute__((ext_vector_type(8)));
typedef float  f32x4  __attribute__((ext_vector_type(4)));

// Problem constants (setup_inputs: b=2, t=8, C=768, h=w=16)
static constexpr int NHEADS = 12, HC = 64, HW = 256, SEQ = 2048;
static constexpr size_t QKV_ONE = (size_t)2 * NHEADS * SEQ * HC;   // 3145728 elems per q/k/v slab
static constexpr size_t NSTRIDE = 768 * 256;                        // 196608

// ---------------------------------------------------------------------------
// prep: blocks 0..3071 = mp_weight rows (wqkv then wproj, proj columns
// permuted to j=head*64+c); blocks 3072..6143 = x fp32->bf16 transpose tiles.
// ---------------------------------------------------------------------------
__global__ __launch_bounds__(256) void va_prep(const float* __restrict__ wqkv,
                                               const float* __restrict__ wproj,
                                               const float* __restrict__ x,
                                               bf16_t* __restrict__ wout,
                                               bf16_t* __restrict__ xt) {
    int blk = blockIdx.x;
    if (blk < 3072) {
        int row = blk;
        bool is_proj = (row >= 2304);
        const float* wr = is_proj ? wproj + (size_t)(row - 2304) * 768
                                  : wqkv + (size_t)row * 768;
        float part = 0.f;
        for (int i = threadIdx.x; i < 768; i += 256) { float v = wr[i]; part += v * v; }
#pragma unroll
        for (int off = 32; off > 0; off >>= 1) part += __shfl_down(part, off, 64);
        __shared__ float red[4];
        if ((threadIdx.x & 63) == 0) red[threadIdx.x >> 6] = part;
        __syncthreads();
        if (threadIdx.x == 0) {
            float s = red[0] + red[1] + red[2] + red[3];
            red[0] = 1.0f / (2.7712813e-3f + sqrtf(s));   // EPS*sqrt(768) + ||w||
        }
        __syncthreads();
        float sc = red[0];
        for (int i = threadIdx.x; i < 768; i += 256) {
            int j = is_proj ? ((i % 12) * 64 + i / 12) : i;
            wout[(size_t)row * 768 + j] = (bf16_t)(wr[i] * sc);
        }
    } else {
        int t = blk - 3072;                 // [0, 3072)
        int n  = t & 15;
        int rest = t >> 4;                  // [0,192)
        int p0 = (rest & 7) * 32;
        int c0 = (rest >> 3) * 32;          // [0,24) * 32
        __shared__ float sm[32][33];
        int tx = threadIdx.x & 31, ty = threadIdx.x >> 5;
        const float* xp = x + (size_t)n * NSTRIDE;
#pragma unroll
        for (int i = 0; i < 4; i++)
            sm[ty + i * 8][tx] = xp[(size_t)(c0 + ty + i * 8) * 256 + p0 + tx];
        __syncthreads();
        bf16_t* xo = xt + (size_t)n * NSTRIDE;
#pragma unroll
        for (int i = 0; i < 4; i++)
            xo[(size_t)(p0 + ty + i * 8) * 768 + c0 + tx] = (bf16_t)sm[tx][ty + i * 8];
    }
}

// ---------------------------------------------------------------------------
// QKV GEMM via MFMA, RoPE + q-scale fused. XCD-remapped by n.
// v3: LDS-staged (m97-family) — verified round 2 (qkv dropped out of top-5).
// ---------------------------------------------------------------------------
__global__ __launch_bounds__(256, 2) void va_qkv_mfma(const bf16_t* __restrict__ Wb,
                                                      const bf16_t* __restrict__ xt,
                                                      bf16_t* __restrict__ qkvb) {
    int idx = blockIdx.x;                   // [0,576)
    int n  = (idx & 7) + 8 * ((idx >> 3) & 1);
    int rest = idx >> 4;                    // [0,36)
    int p0 = (rest & 1) * 128;
    int m0 = (rest >> 1) * 128;             // [0,18)*128
    int tid = threadIdx.x;
    int lane = tid & 63, w = tid >> 6;
    int lo = lane & 15, hi = lane >> 4;
    int wm = w >> 1, wn = w & 1;
    int lx = lo & 7;                        // read-side swizzle key (= row&7)

    __shared__ bf16_t Asm[128 * 64];        // [row 0..127][k 0..63], 128B rows
    __shared__ bf16_t Bsm[128 * 64];

    // staging: thread t owns rows (t>>3)+32i, 16B chunk c=(t&7); dest chunk
    // is XOR-swizzled by row&7 (invariant under +32).
    int srow = tid >> 3, schunk = tid & 7;
    const bf16_t* Ag = Wb + (size_t)(m0 + srow) * 768 + schunk * 8;
    const bf16_t* Bg = xt + (size_t)n * NSTRIDE + (size_t)(p0 + srow) * 768 + schunk * 8;
    int sdst = srow * 128 + ((schunk ^ (srow & 7)) << 4);

    f32x4 acc[4][4];
#pragma unroll
    for (int mt = 0; mt < 4; mt++)
#pragma unroll
        for (int nt = 0; nt < 4; nt++) acc[mt][nt] = (f32x4){0.f, 0.f, 0.f, 0.f};

    bf16x8 sa[4], sb[4];                    // stage registers (4 rows each of A,B)

    auto gload = [&](int k0) {
#pragma unroll
        for (int i = 0; i < 4; i++) {
            sa[i] = *(const bf16x8*)(Ag + (size_t)i * 32 * 768 + k0);
            sb[i] = *(const bf16x8*)(Bg + (size_t)i * 32 * 768 + k0);
        }
    };
    auto swrite = [&]() {
        char* Ac = (char*)Asm;
        char* Bc = (char*)Bsm;
#pragma unroll
        for (int i = 0; i < 4; i++) {
            *(bf16x8*)(Ac + sdst + i * 32 * 128) = sa[i];
            *(bf16x8*)(Bc + sdst + i * 32 * 128) = sb[i];
        }
    };

    gload(0);
    for (int s = 0; s < 12; s++) {
        __syncthreads();                    // previous tile's ds_reads complete
        swrite();                           // (compiler waits vmcnt for sa/sb)
        if (s < 11) gload((s + 1) * 64);    // issue next tile early; drains
                                            // under this tile's MFMA
        __syncthreads();                    // tile visible
#pragma unroll
        for (int kk = 0; kk < 64; kk += 32) {
            int cb = kk >> 3;               // chunk base: 0 or 4
            bf16x8 af[4], bfr[4];
            const char* Ac = (const char*)Asm;
            const char* Bc = (const char*)Bsm;
#pragma unroll
            for (int mt = 0; mt < 4; mt++) {
                int row = wm * 64 + mt * 16 + lo;
                af[mt] = *(const bf16x8*)(Ac + row * 128 + (((cb + hi) ^ lx) << 4));
            }
#pragma unroll
            for (int nt = 0; nt < 4; nt++) {
                int row = wn * 64 + nt * 16 + lo;
                bfr[nt] = *(const bf16x8*)(Bc + row * 128 + (((cb + hi) ^ lx) << 4));
            }
#pragma unroll
            for (int mt = 0; mt < 4; mt++)
#pragma unroll
                for (int nt = 0; nt < 4; nt++)
                    acc[mt][nt] = __builtin_amdgcn_mfma_f32_16x16x32_bf16(af[mt], bfr[nt], acc[mt][nt], 0, 0, 0);
        }
    }

    int head_global = (m0 + wm * 64) >> 6;
    int qkv_idx = head_global / 12;
    int head    = head_global % 12;
    int b = n >> 3, tt = n & 7;
    int bm = b * 12 + head;
    if (qkv_idx < 2) {
        float qsc = (qkv_idx == 0) ? 0.125f : 1.0f;
        float ttf = (float)tt;
#pragma unroll
        for (int mt = 0; mt < 2; mt++)
#pragma unroll
            for (int r = 0; r < 4; r++) {
                int j = mt * 16 + hi * 4 + r;
                float ang = ttf * __expf(-(float)j * 0.2878231366242557f);
                float cs = __cosf(ang), sn = __sinf(ang);
#pragma unroll
                for (int nt = 0; nt < 4; nt++) {
                    float x1 = acc[mt][nt][r], x2 = acc[mt + 2][nt][r];
                    acc[mt][nt][r]     = (x1 * cs - x2 * sn) * qsc;
                    acc[mt + 2][nt][r] = (x1 * sn + x2 * cs) * qsc;
                }
            }
        bf16_t* dst = qkvb + (size_t)qkv_idx * QKV_ONE + ((size_t)bm * SEQ + (size_t)tt * HW) * HC;
#pragma unroll
        for (int mt = 0; mt < 4; mt++)
#pragma unroll
            for (int nt = 0; nt < 4; nt++)
#pragma unroll
                for (int r = 0; r < 4; r++) {
                    int cc = mt * 16 + hi * 4 + r;
                    int p  = p0 + wn * 64 + nt * 16 + lo;
                    dst[(size_t)p * HC + cc] = (bf16_t)acc[mt][nt][r];
                }
    } else {
        bf16_t* dst = qkvb + 2 * QKV_ONE + (size_t)bm * HC * SEQ + (size_t)tt * HW;
#pragma unroll
        for (int mt = 0; mt < 4; mt++)
#pragma unroll
            for (int nt = 0; nt < 4; nt++)
#pragma unroll
                for (int r = 0; r < 4; r++) {
                    int cc = mt * 16 + hi * 4 + r;
                    int p  = p0 + wn * 64 + nt * 16 + lo;
                    dst[(size_t)cc * SEQ + p] = (bf16_t)acc[mt][nt][r];
                }
    }
}

// ---------------------------------------------------------------------------
// MFMA flash attention v11: v10 + spill fix + real prefetch distance.
// v10 post-mortem: dur flat at 66us with occupancy 4.7->23% AND +64 MB of
// unexplainable traffic (WRITE 6->55 MB with only 6.3 MB of yob stores) =
// scratch spill. __launch_bounds__(256,3) capped the allocator (VGPR_Count
// DROPPED 96->84 vs v9 at identical per-wave demand); spill-added latency
// cancelled the occupancy gain exactly.
// v11: (a) __launch_bounds__(256,2) — 256-reg budget, no spill (33 KB LDS
// still gives 2 blocks/CU); (b) spend the freed regs on prefetch distance:
// V(kpos) issued at loop TOP (consumed ~1000cy later in PV, hides under
// S/exp/pack), K(kpos+256) double-buffered — issued right after the S phase
// consumes K(kpos), hides under pack+pb+PV. Per-step chain was ~4900cy of
// mostly exposed K/V latency (v9 measurement). MFMA/exp/pack/combine math
// byte-identical to v10. Dead striping arithmetic deleted (s == blk).
// ---------------------------------------------------------------------------
__global__ __launch_bounds__(256, 2) void va_attn(const bf16_t* __restrict__ qkvb,
                                                  bf16_t* __restrict__ yob) {
    int s = blockIdx.x;                     // [0,768), f-descending heavy-first
    int f = 7 - (s / 96);
    int within = s % 96;
    int bm = within % 24;                   // bm%8 == s%8 -> XCD-pinned per bm
    int qs = within / 24;                   // [0,4) 64-query subtile of frame

    int tid = threadIdx.x;
    int w = tid >> 6, lane = tid & 63;      // w = kf-slice of this wave
    int lo = lane & 15, hi = lane >> 4;
    int lx = lo & 7;                        // swizzle key

    const bf16_t* qbase = qkvb + (size_t)bm * SEQ * HC;
    const bf16_t* kbase = qkvb + QKV_ONE + (size_t)bm * SEQ * HC;
    const bf16_t* vbase = qkvb + 2 * QKV_ONE + (size_t)bm * HC * SEQ;

    __shared__ bf16_t PBF[4][64 * 64];      // wave-private P^T / O-partial slabs
    __shared__ float  Lsm[4][64];           // per-wave l vectors
    bf16_t* PBw = PBF[w];

    // Q B-frags: queries f*256 + qs*64 .. +63 (q pre-scaled 0.125)
    const bf16_t* qrow = qbase + (size_t)(f * 256 + qs * 64 + lo) * HC;
    bf16x8 qf[4][2];
#pragma unroll
    for (int nq = 0; nq < 4; nq++) {
        qf[nq][0] = *(const bf16x8*)(qrow + (size_t)nq * 16 * HC + hi * 8);
        qf[nq][1] = *(const bf16x8*)(qrow + (size_t)nq * 16 * HC + 32 + hi * 8);
    }
    f32x4 o[4][4];
#pragma unroll
    for (int ct = 0; ct < 4; ct++)
#pragma unroll
        for (int nq = 0; nq < 4; nq++) o[ct][nq] = (f32x4){0.f, 0.f, 0.f, 0.f};
    float l4[4] = {0.f, 0.f, 0.f, 0.f};

    int kend = (f + 1) * 256;

    // ---- K prologue: first tile for this wave
    bf16x8 ka[8];
    {
        const bf16_t* kp = kbase + (size_t)(w * 64 + lo) * HC + hi * 8;
#pragma unroll
        for (int mt = 0; mt < 4; mt++) {
            ka[2 * mt]     = *(const bf16x8*)(kp + (size_t)mt * 16 * HC);
            ka[2 * mt + 1] = *(const bf16x8*)(kp + (size_t)mt * 16 * HC + 32);
        }
    }

    for (int kpos = w * 64; kpos < kend; kpos += 256) {
        // ---- V(kpos): issue FIRST — consumed only in PV, hides under S phase
        const bf16_t* vp = vbase + (size_t)(lo) * SEQ + kpos + hi * 8;
        bf16x8 va[8];
#pragma unroll
        for (int ct = 0; ct < 4; ct++) {
            va[2 * ct]     = *(const bf16x8*)(vp + (size_t)ct * 16 * SEQ);
            va[2 * ct + 1] = *(const bf16x8*)(vp + (size_t)ct * 16 * SEQ + 32);
        }
        // ---- S^T = K·Q^T, exp, P^T -> wave-private LDS (consumes ka)
#pragma unroll
        for (int mt = 0; mt < 4; mt++) {
#pragma unroll
            for (int nq = 0; nq < 4; nq++) {
                f32x4 sacc = (f32x4){0.f, 0.f, 0.f, 0.f};
                sacc = __builtin_amdgcn_mfma_f32_16x16x32_bf16(ka[2 * mt], qf[nq][0], sacc, 0, 0, 0);
                sacc = __builtin_amdgcn_mfma_f32_16x16x32_bf16(ka[2 * mt + 1], qf[nq][1], sacc, 0, 0, 0);
                bf16x4 pk;
#pragma unroll
                for (int r = 0; r < 4; r++) {
                    float p = __expf(sacc[r]);
                    l4[nq] += p;
                    pk[r] = (bf16_t)p;
                }
                *(bf16x4*)(PBw + (nq * 16 + lo) * 64 +
                           (((2 * mt + (hi >> 1)) ^ lx) * 8) + (hi & 1) * 4) = pk;
            }
        }
        // ---- K(kpos+256) prefetch: ka free now; hides under pb+PV.
        // Last iter: clamp to kpos (harmless warm reload, never consumed).
        int knext = (kpos + 256 < kend) ? kpos + 256 : kpos;
        bf16x8 kan[8];
        {
            const bf16_t* kp = kbase + (size_t)(knext + lo) * HC + hi * 8;
#pragma unroll
            for (int mt = 0; mt < 4; mt++) {
                kan[2 * mt]     = *(const bf16x8*)(kp + (size_t)mt * 16 * HC);
                kan[2 * mt + 1] = *(const bf16x8*)(kp + (size_t)mt * 16 * HC + 32);
            }
        }
        // ---- P^T B-frags back from LDS (same wave, DS in-order)
        bf16x8 pb0[4], pb1[4];
#pragma unroll
        for (int nq = 0; nq < 4; nq++) {
            pb0[nq] = *(const bf16x8*)(PBw + (nq * 16 + lo) * 64 + (hi ^ lx) * 8);
            pb1[nq] = *(const bf16x8*)(PBw + (nq * 16 + lo) * 64 + ((4 + hi) ^ lx) * 8);
        }
        // ---- O^T += V^T·P^T
#pragma unroll
        for (int ct = 0; ct < 4; ct++)
#pragma unroll
            for (int nq = 0; nq < 4; nq++) {
                o[ct][nq] = __builtin_amdgcn_mfma_f32_16x16x32_bf16(va[2 * ct], pb0[nq], o[ct][nq], 0, 0, 0);
                o[ct][nq] = __builtin_amdgcn_mfma_f32_16x16x32_bf16(va[2 * ct + 1], pb1[nq], o[ct][nq], 0, 0, 0);
            }
        // ---- rotate K buffers
#pragma unroll
        for (int i = 0; i < 8; i++) ka[i] = kan[i];
    }
    // ---- per-wave l reduction (butterfly over hi) + store to LDS
#pragma unroll
    for (int nq = 0; nq < 4; nq++) {
        l4[nq] += __shfl_xor(l4[nq], 16, 64);
        l4[nq] += __shfl_xor(l4[nq], 32, 64);
    }
    if (hi == 0) {
#pragma unroll
        for (int nq = 0; nq < 4; nq++) Lsm[w][nq * 16 + lo] = l4[nq];
    }
    // ---- pack UNNORMALIZED O-partial (bf16) into wave-private slab
#pragma unroll
    for (int ct = 0; ct < 4; ct++)
#pragma unroll
        for (int nq = 0; nq < 4; nq++) {
            bf16x4 ov;
#pragma unroll
            for (int r = 0; r < 4; r++) ov[r] = (bf16_t)o[ct][nq][r];
            *(bf16x4*)(PBw + (nq * 16 + lo) * 64 +
                       (((2 * ct + (hi >> 1)) ^ lx) * 8) + (hi & 1) * 4) = ov;
        }
    __syncthreads();
    // ---- combine 4 slabs + 4 l's in fp32, normalize, store yob
    int head = bm % 12, b = bm / 12;
    bf16_t* yb = yob + (size_t)(b * 8 + f) * NSTRIDE + (size_t)(qs * 64) * 768 + head * 64;
#pragma unroll
    for (int i = 0; i < 2; i++) {
        int c = i * 256 + tid;              // [0,512) chunk: 64 rows x 8 chunks
        int row = c >> 3, j = c & 7;
        int off = row * 64 + ((j ^ (row & 7)) * 8);
        float invl = 1.0f / (Lsm[0][row] + Lsm[1][row] + Lsm[2][row] + Lsm[3][row]);
        bf16x8 p0 = *(const bf16x8*)(PBF[0] + off);
        bf16x8 p1 = *(const bf16x8*)(PBF[1] + off);
        bf16x8 p2 = *(const bf16x8*)(PBF[2] + off);
        bf16x8 p3 = *(const bf16x8*)(PBF[3] + off);
        bf16x8 o8;
#pragma unroll
        for (int r = 0; r < 8; r++)
            o8[r] = (bf16_t)(((float)p0[r] + (float)p1[r] + (float)p2[r] + (float)p3[r]) * invl);
        *(bf16x8*)(yb + (size_t)row * 768 + j * 8) = o8;
    }
}

// ---------------------------------------------------------------------------
// Proj GEMM via MFMA + mp_sum. XCD-remapped by n. (unchanged)
// ---------------------------------------------------------------------------
__global__ __launch_bounds__(256, 2) void va_proj_mfma(const bf16_t* __restrict__ Wb,
                                                       const bf16_t* __restrict__ yob,
                                                       const float* __restrict__ x,
                                                       float* __restrict__ out) {
    int idx = blockIdx.x;                   // [0,384)
    int n  = (idx & 7) + 8 * ((idx >> 3) & 1);
    int rest = idx >> 4;                    // [0,24)
    int p0 = (rest & 1) * 128;
    int m0 = (rest >> 1) * 64;              // [0,12)*64
    int tid = threadIdx.x;
    int lane = tid & 63, w = tid >> 6;      // w = column-slice index [0,4)
    int lo = lane & 15, hi = lane >> 4;

    const bf16_t* Ap = Wb + (size_t)(m0 + lo) * 768 + hi * 8;
    const bf16_t* Bp = yob + (size_t)n * NSTRIDE + (size_t)(p0 + w * 32 + lo) * 768 + hi * 8;

    f32x4 acc[4][2];
#pragma unroll
    for (int mt = 0; mt < 4; mt++)
#pragma unroll
        for (int nt = 0; nt < 2; nt++) acc[mt][nt] = (f32x4){0.f, 0.f, 0.f, 0.f};

    for (int k0 = 0; k0 < 768; k0 += 32) {
        bf16x8 af[4], bfr[2];
#pragma unroll
        for (int mt = 0; mt < 4; mt++)
            af[mt] = *(const bf16x8*)(Ap + (size_t)mt * 16 * 768 + k0);
#pragma unroll
        for (int nt = 0; nt < 2; nt++)
            bfr[nt] = *(const bf16x8*)(Bp + (size_t)nt * 16 * 768 + k0);
#pragma unroll
        for (int mt = 0; mt < 4; mt++)
#pragma unroll
            for (int nt = 0; nt < 2; nt++)
                acc[mt][nt] = __builtin_amdgcn_mfma_f32_16x16x32_bf16(af[mt], bfr[nt], acc[mt][nt], 0, 0, 0);
    }

    const float* xn = x + (size_t)n * NSTRIDE;
    float* on = out + (size_t)n * NSTRIDE;
#pragma unroll
    for (int mt = 0; mt < 4; mt++)
#pragma unroll
        for (int nt = 0; nt < 2; nt++)
#pragma unroll
            for (int r = 0; r < 4; r++) {
                int oo = m0 + mt * 16 + hi * 4 + r;
                int p  = p0 + w * 32 + nt * 16 + lo;
                size_t idx2 = (size_t)oo * 256 + p;
                on[idx2] = (xn[idx2] * 0.7f + acc[mt][nt][r] * 0.3f) * 1.3130643f;
            }
}

// ---------------------------------------------------------------------------
extern "C" void kernel_launch(void* const* d_in, const int* in_sizes, int n_in,
                              void* d_out, int out_size, void* d_ws, size_t ws_size,
                              hipStream_t stream) {
    const float* x     = (const float*)d_in[0];
    const float* wqkv  = (const float*)d_in[1];
    const float* wproj = (const float*)d_in[2];
    float* out = (float*)d_out;

    // Workspace layout kept identical to v8 (Opart/lpart slots now unused).
    bf16_t* Opart = (bf16_t*)d_ws;                             // (unused)
    float*  lpart = (float*)(Opart + (size_t)24 * 36 * 16384); // (unused)
    bf16_t* wqkv_nb  = (bf16_t*)(lpart + (size_t)24 * 36 * 256);
    bf16_t* xt       = wqkv_nb + (size_t)3072 * 768;
    bf16_t* qkvb     = xt + NSTRIDE * 16;
    bf16_t* yob      = qkvb + 3 * QKV_ONE;

    va_prep<<<6144, 256, 0, stream>>>(wqkv, wproj, x, wqkv_nb, xt);
    va_qkv_mfma<<<576, 256, 0, stream>>>(wqkv_nb, xt, qkvb);
    va_attn<<<768, 256, 0, stream>>>(qkvb, yob);
    va_proj_mfma<<<384, 256, 0, stream>>>(wqkv_nb + (size_t)2304 * 768, yob, x, out);
}

// Round 6
// 149.819 us; speedup vs baseline: 1.7049x; 1.1430x over previous
//
#include <hip/hip_runtime.h>

typedef __bf16 bf16_t;
typedef __bf16 bf16x4 __attribute__((ext_vector_type(4)));
typedef __bf16 bf16x8 __attribute__((ext_vector_type(8)));
typedef float  f32x4  __attribute__((ext_vector_type(4)));

// Problem constants (setup_inputs: b=2, t=8, C=768, h=w=16)
static constexpr int NHEADS = 12, HC = 64, HW = 256, SEQ = 2048;
static constexpr size_t QKV_ONE = (size_t)2 * NHEADS * SEQ * HC;   // 3145728 elems per q/k/v slab
static constexpr size_t NSTRIDE = 768 * 256;                        // 196608

// ---------------------------------------------------------------------------
// prep: blocks 0..3071 = mp_weight rows (wqkv then wproj, proj columns
// permuted to j=head*64+c); blocks 3072..6143 = x fp32->bf16 transpose tiles.
// ---------------------------------------------------------------------------
__global__ __launch_bounds__(256) void va_prep(const float* __restrict__ wqkv,
                                               const float* __restrict__ wproj,
                                               const float* __restrict__ x,
                                               bf16_t* __restrict__ wout,
                                               bf16_t* __restrict__ xt) {
    int blk = blockIdx.x;
    if (blk < 3072) {
        int row = blk;
        bool is_proj = (row >= 2304);
        const float* wr = is_proj ? wproj + (size_t)(row - 2304) * 768
                                  : wqkv + (size_t)row * 768;
        float part = 0.f;
        for (int i = threadIdx.x; i < 768; i += 256) { float v = wr[i]; part += v * v; }
#pragma unroll
        for (int off = 32; off > 0; off >>= 1) part += __shfl_down(part, off, 64);
        __shared__ float red[4];
        if ((threadIdx.x & 63) == 0) red[threadIdx.x >> 6] = part;
        __syncthreads();
        if (threadIdx.x == 0) {
            float s = red[0] + red[1] + red[2] + red[3];
            red[0] = 1.0f / (2.7712813e-3f + sqrtf(s));   // EPS*sqrt(768) + ||w||
        }
        __syncthreads();
        float sc = red[0];
        for (int i = threadIdx.x; i < 768; i += 256) {
            int j = is_proj ? ((i % 12) * 64 + i / 12) : i;
            wout[(size_t)row * 768 + j] = (bf16_t)(wr[i] * sc);
        }
    } else {
        int t = blk - 3072;                 // [0, 3072)
        int n  = t & 15;
        int rest = t >> 4;                  // [0,192)
        int p0 = (rest & 7) * 32;
        int c0 = (rest >> 3) * 32;          // [0,24) * 32
        __shared__ float sm[32][33];
        int tx = threadIdx.x & 31, ty = threadIdx.x >> 5;
        const float* xp = x + (size_t)n * NSTRIDE;
#pragma unroll
        for (int i = 0; i < 4; i++)
            sm[ty + i * 8][tx] = xp[(size_t)(c0 + ty + i * 8) * 256 + p0 + tx];
        __syncthreads();
        bf16_t* xo = xt + (size_t)n * NSTRIDE;
#pragma unroll
        for (int i = 0; i < 4; i++)
            xo[(size_t)(p0 + ty + i * 8) * 768 + c0 + tx] = (bf16_t)sm[tx][ty + i * 8];
    }
}

// ---------------------------------------------------------------------------
// QKV GEMM via MFMA, RoPE + q-scale fused. XCD-remapped by n.
// v3: LDS-staged (m97-family) — verified round 2.
// v4: q-scale folds log2e (0.125*1.4426950 = 0.18033688) so attn can use a
// raw v_exp_f32 (2^x) instead of __expf's mul+exp. exp(S*0.125) ==
// 2^(S*0.18033688).
// ---------------------------------------------------------------------------
__global__ __launch_bounds__(256, 2) void va_qkv_mfma(const bf16_t* __restrict__ Wb,
                                                      const bf16_t* __restrict__ xt,
                                                      bf16_t* __restrict__ qkvb) {
    int idx = blockIdx.x;                   // [0,576)
    int n  = (idx & 7) + 8 * ((idx >> 3) & 1);
    int rest = idx >> 4;                    // [0,36)
    int p0 = (rest & 1) * 128;
    int m0 = (rest >> 1) * 128;             // [0,18)*128
    int tid = threadIdx.x;
    int lane = tid & 63, w = tid >> 6;
    int lo = lane & 15, hi = lane >> 4;
    int wm = w >> 1, wn = w & 1;
    int lx = lo & 7;                        // read-side swizzle key (= row&7)

    __shared__ bf16_t Asm[128 * 64];        // [row 0..127][k 0..63], 128B rows
    __shared__ bf16_t Bsm[128 * 64];

    // staging: thread t owns rows (t>>3)+32i, 16B chunk c=(t&7); dest chunk
    // is XOR-swizzled by row&7 (invariant under +32).
    int srow = tid >> 3, schunk = tid & 7;
    const bf16_t* Ag = Wb + (size_t)(m0 + srow) * 768 + schunk * 8;
    const bf16_t* Bg = xt + (size_t)n * NSTRIDE + (size_t)(p0 + srow) * 768 + schunk * 8;
    int sdst = srow * 128 + ((schunk ^ (srow & 7)) << 4);

    f32x4 acc[4][4];
#pragma unroll
    for (int mt = 0; mt < 4; mt++)
#pragma unroll
        for (int nt = 0; nt < 4; nt++) acc[mt][nt] = (f32x4){0.f, 0.f, 0.f, 0.f};

    bf16x8 sa[4], sb[4];                    // stage registers (4 rows each of A,B)

    auto gload = [&](int k0) {
#pragma unroll
        for (int i = 0; i < 4; i++) {
            sa[i] = *(const bf16x8*)(Ag + (size_t)i * 32 * 768 + k0);
            sb[i] = *(const bf16x8*)(Bg + (size_t)i * 32 * 768 + k0);
        }
    };
    auto swrite = [&]() {
        char* Ac = (char*)Asm;
        char* Bc = (char*)Bsm;
#pragma unroll
        for (int i = 0; i < 4; i++) {
            *(bf16x8*)(Ac + sdst + i * 32 * 128) = sa[i];
            *(bf16x8*)(Bc + sdst + i * 32 * 128) = sb[i];
        }
    };

    gload(0);
    for (int s = 0; s < 12; s++) {
        __syncthreads();                    // previous tile's ds_reads complete
        swrite();                           // (compiler waits vmcnt for sa/sb)
        if (s < 11) gload((s + 1) * 64);    // issue next tile early; drains
                                            // under this tile's MFMA
        __syncthreads();                    // tile visible
#pragma unroll
        for (int kk = 0; kk < 64; kk += 32) {
            int cb = kk >> 3;               // chunk base: 0 or 4
            bf16x8 af[4], bfr[4];
            const char* Ac = (const char*)Asm;
            const char* Bc = (const char*)Bsm;
#pragma unroll
            for (int mt = 0; mt < 4; mt++) {
                int row = wm * 64 + mt * 16 + lo;
                af[mt] = *(const bf16x8*)(Ac + row * 128 + (((cb + hi) ^ lx) << 4));
            }
#pragma unroll
            for (int nt = 0; nt < 4; nt++) {
                int row = wn * 64 + nt * 16 + lo;
                bfr[nt] = *(const bf16x8*)(Bc + row * 128 + (((cb + hi) ^ lx) << 4));
            }
#pragma unroll
            for (int mt = 0; mt < 4; mt++)
#pragma unroll
                for (int nt = 0; nt < 4; nt++)
                    acc[mt][nt] = __builtin_amdgcn_mfma_f32_16x16x32_bf16(af[mt], bfr[nt], acc[mt][nt], 0, 0, 0);
        }
    }

    int head_global = (m0 + wm * 64) >> 6;
    int qkv_idx = head_global / 12;
    int head    = head_global % 12;
    int b = n >> 3, tt = n & 7;
    int bm = b * 12 + head;
    if (qkv_idx < 2) {
        // q pre-scale now folds log2e: exp(S/8) computed as 2^(S*0.18033688)
        float qsc = (qkv_idx == 0) ? 0.18033688011f : 1.0f;
        float ttf = (float)tt;
#pragma unroll
        for (int mt = 0; mt < 2; mt++)
#pragma unroll
            for (int r = 0; r < 4; r++) {
                int j = mt * 16 + hi * 4 + r;
                float ang = ttf * __expf(-(float)j * 0.2878231366242557f);
                float cs = __cosf(ang), sn = __sinf(ang);
#pragma unroll
                for (int nt = 0; nt < 4; nt++) {
                    float x1 = acc[mt][nt][r], x2 = acc[mt + 2][nt][r];
                    acc[mt][nt][r]     = (x1 * cs - x2 * sn) * qsc;
                    acc[mt + 2][nt][r] = (x1 * sn + x2 * cs) * qsc;
                }
            }
        bf16_t* dst = qkvb + (size_t)qkv_idx * QKV_ONE + ((size_t)bm * SEQ + (size_t)tt * HW) * HC;
#pragma unroll
        for (int mt = 0; mt < 4; mt++)
#pragma unroll
            for (int nt = 0; nt < 4; nt++)
#pragma unroll
                for (int r = 0; r < 4; r++) {
                    int cc = mt * 16 + hi * 4 + r;
                    int p  = p0 + wn * 64 + nt * 16 + lo;
                    dst[(size_t)p * HC + cc] = (bf16_t)acc[mt][nt][r];
                }
    } else {
        bf16_t* dst = qkvb + 2 * QKV_ONE + (size_t)bm * HC * SEQ + (size_t)tt * HW;
#pragma unroll
        for (int mt = 0; mt < 4; mt++)
#pragma unroll
            for (int nt = 0; nt < 4; nt++)
#pragma unroll
                for (int r = 0; r < 4; r++) {
                    int cc = mt * 16 + hi * 4 + r;
                    int p  = p0 + wn * 64 + nt * 16 + lo;
                    dst[(size_t)cc * SEQ + p] = (bf16_t)acc[mt][nt][r];
                }
    }
}

// ---------------------------------------------------------------------------
// MFMA flash attention v12: v11 + split-phase DS overlap + raw v_exp + setprio.
// v11 post-mortem: spill fix + prefetch landed (attn ~66 -> ~37us, dropped
// below the fill in top-5). Remaining per-step chain ~1644cy vs ~1200cy of
// issue work — the exposed piece is the pack->pb LDS turnaround and __expf's
// leading v_mul. v12:
//  (a) pb0 (keys 0-31, chunks 0-3) depends only on mt=0,1 pack-writes
//      (disjoint chunk sets) -> issue pb0 reads BETWEEN S(mt01) and S(mt23);
//      pb1 issued after K-prefetch, hidden under PV-half-A (va[2ct]*pb0).
//      DS is in-order per wave -> correctness unchanged.
//  (b) exp via raw v_exp_f32 (2^x); log2e folded into qkv's q-scale.
//  (c) s_setprio(1) around MFMA clusters (attn measured +4-7%, m191 case:
//      independent waves, no barriers).
// Math identical to v11 otherwise.
// ---------------------------------------------------------------------------
__global__ __launch_bounds__(256, 2) void va_attn(const bf16_t* __restrict__ qkvb,
                                                  bf16_t* __restrict__ yob) {
    int s = blockIdx.x;                     // [0,768), f-descending heavy-first
    int f = 7 - (s / 96);
    int within = s % 96;
    int bm = within % 24;                   // bm%8 == s%8 -> XCD-pinned per bm
    int qs = within / 24;                   // [0,4) 64-query subtile of frame

    int tid = threadIdx.x;
    int w = tid >> 6, lane = tid & 63;      // w = kf-slice of this wave
    int lo = lane & 15, hi = lane >> 4;
    int lx = lo & 7;                        // swizzle key

    const bf16_t* qbase = qkvb + (size_t)bm * SEQ * HC;
    const bf16_t* kbase = qkvb + QKV_ONE + (size_t)bm * SEQ * HC;
    const bf16_t* vbase = qkvb + 2 * QKV_ONE + (size_t)bm * HC * SEQ;

    __shared__ bf16_t PBF[4][64 * 64];      // wave-private P^T / O-partial slabs
    __shared__ float  Lsm[4][64];           // per-wave l vectors
    bf16_t* PBw = PBF[w];

    // Q B-frags: queries f*256 + qs*64 .. +63 (q pre-scaled 0.125*log2e)
    const bf16_t* qrow = qbase + (size_t)(f * 256 + qs * 64 + lo) * HC;
    bf16x8 qf[4][2];
#pragma unroll
    for (int nq = 0; nq < 4; nq++) {
        qf[nq][0] = *(const bf16x8*)(qrow + (size_t)nq * 16 * HC + hi * 8);
        qf[nq][1] = *(const bf16x8*)(qrow + (size_t)nq * 16 * HC + 32 + hi * 8);
    }
    f32x4 o[4][4];
#pragma unroll
    for (int ct = 0; ct < 4; ct++)
#pragma unroll
        for (int nq = 0; nq < 4; nq++) o[ct][nq] = (f32x4){0.f, 0.f, 0.f, 0.f};
    float l4[4] = {0.f, 0.f, 0.f, 0.f};

    int kend = (f + 1) * 256;

    // ---- K prologue: first tile for this wave
    bf16x8 ka[8];
    {
        const bf16_t* kp = kbase + (size_t)(w * 64 + lo) * HC + hi * 8;
#pragma unroll
        for (int mt = 0; mt < 4; mt++) {
            ka[2 * mt]     = *(const bf16x8*)(kp + (size_t)mt * 16 * HC);
            ka[2 * mt + 1] = *(const bf16x8*)(kp + (size_t)mt * 16 * HC + 32);
        }
    }

    for (int kpos = w * 64; kpos < kend; kpos += 256) {
        // ---- V(kpos): issue FIRST — consumed only in PV, hides under S phase
        const bf16_t* vp = vbase + (size_t)(lo) * SEQ + kpos + hi * 8;
        bf16x8 va[8];
#pragma unroll
        for (int ct = 0; ct < 4; ct++) {
            va[2 * ct]     = *(const bf16x8*)(vp + (size_t)ct * 16 * SEQ);
            va[2 * ct + 1] = *(const bf16x8*)(vp + (size_t)ct * 16 * SEQ + 32);
        }
        // ---- S^T (keys 0..31): mt=0,1 -> exp2 -> pack (chunks 0-3)
        __builtin_amdgcn_s_setprio(1);
#pragma unroll
        for (int mt = 0; mt < 2; mt++) {
#pragma unroll
            for (int nq = 0; nq < 4; nq++) {
                f32x4 sacc = (f32x4){0.f, 0.f, 0.f, 0.f};
                sacc = __builtin_amdgcn_mfma_f32_16x16x32_bf16(ka[2 * mt], qf[nq][0], sacc, 0, 0, 0);
                sacc = __builtin_amdgcn_mfma_f32_16x16x32_bf16(ka[2 * mt + 1], qf[nq][1], sacc, 0, 0, 0);
                bf16x4 pk;
#pragma unroll
                for (int r = 0; r < 4; r++) {
                    float p;
                    asm("v_exp_f32 %0, %1" : "=v"(p) : "v"(sacc[r]));  // 2^x
                    l4[nq] += p;
                    pk[r] = (bf16_t)p;
                }
                *(bf16x4*)(PBw + (nq * 16 + lo) * 64 +
                           (((2 * mt + (hi >> 1)) ^ lx) * 8) + (hi & 1) * 4) = pk;
            }
        }
        __builtin_amdgcn_s_setprio(0);
        // ---- pb0 (keys 0-31): only needs mt=0,1 writes; latency hides
        // under the S(mt=2,3) MFMA below (DS in-order per wave).
        bf16x8 pb0[4], pb1[4];
#pragma unroll
        for (int nq = 0; nq < 4; nq++)
            pb0[nq] = *(const bf16x8*)(PBw + (nq * 16 + lo) * 64 + (hi ^ lx) * 8);
        // ---- S^T (keys 32..63): mt=2,3 -> exp2 -> pack (chunks 4-7)
        __builtin_amdgcn_s_setprio(1);
#pragma unroll
        for (int mt = 2; mt < 4; mt++) {
#pragma unroll
            for (int nq = 0; nq < 4; nq++) {
                f32x4 sacc = (f32x4){0.f, 0.f, 0.f, 0.f};
                sacc = __builtin_amdgcn_mfma_f32_16x16x32_bf16(ka[2 * mt], qf[nq][0], sacc, 0, 0, 0);
                sacc = __builtin_amdgcn_mfma_f32_16x16x32_bf16(ka[2 * mt + 1], qf[nq][1], sacc, 0, 0, 0);
                bf16x4 pk;
#pragma unroll
                for (int r = 0; r < 4; r++) {
                    float p;
                    asm("v_exp_f32 %0, %1" : "=v"(p) : "v"(sacc[r]));  // 2^x
                    l4[nq] += p;
                    pk[r] = (bf16_t)p;
                }
                *(bf16x4*)(PBw + (nq * 16 + lo) * 64 +
                           (((2 * mt + (hi >> 1)) ^ lx) * 8) + (hi & 1) * 4) = pk;
            }
        }
        __builtin_amdgcn_s_setprio(0);
        // ---- K(kpos+256) prefetch: ka free now; hides under PV.
        int knext = (kpos + 256 < kend) ? kpos + 256 : kpos;
        bf16x8 kan[8];
        {
            const bf16_t* kp = kbase + (size_t)(knext + lo) * HC + hi * 8;
#pragma unroll
            for (int mt = 0; mt < 4; mt++) {
                kan[2 * mt]     = *(const bf16x8*)(kp + (size_t)mt * 16 * HC);
                kan[2 * mt + 1] = *(const bf16x8*)(kp + (size_t)mt * 16 * HC + 32);
            }
        }
        // ---- pb1 (keys 32-63): latency hides under PV-half-A below
#pragma unroll
        for (int nq = 0; nq < 4; nq++)
            pb1[nq] = *(const bf16x8*)(PBw + (nq * 16 + lo) * 64 + ((4 + hi) ^ lx) * 8);
        // ---- O^T += V^T·P^T : half A (keys 0-31, pb0), then half B (pb1)
        __builtin_amdgcn_s_setprio(1);
#pragma unroll
        for (int ct = 0; ct < 4; ct++)
#pragma unroll
            for (int nq = 0; nq < 4; nq++)
                o[ct][nq] = __builtin_amdgcn_mfma_f32_16x16x32_bf16(va[2 * ct], pb0[nq], o[ct][nq], 0, 0, 0);
#pragma unroll
        for (int ct = 0; ct < 4; ct++)
#pragma unroll
            for (int nq = 0; nq < 4; nq++)
                o[ct][nq] = __builtin_amdgcn_mfma_f32_16x16x32_bf16(va[2 * ct + 1], pb1[nq], o[ct][nq], 0, 0, 0);
        __builtin_amdgcn_s_setprio(0);
        // ---- rotate K buffers
#pragma unroll
        for (int i = 0; i < 8; i++) ka[i] = kan[i];
    }
    // ---- per-wave l reduction (butterfly over hi) + store to LDS
#pragma unroll
    for (int nq = 0; nq < 4; nq++) {
        l4[nq] += __shfl_xor(l4[nq], 16, 64);
        l4[nq] += __shfl_xor(l4[nq], 32, 64);
    }
    if (hi == 0) {
#pragma unroll
        for (int nq = 0; nq < 4; nq++) Lsm[w][nq * 16 + lo] = l4[nq];
    }
    // ---- pack UNNORMALIZED O-partial (bf16) into wave-private slab
#pragma unroll
    for (int ct = 0; ct < 4; ct++)
#pragma unroll
        for (int nq = 0; nq < 4; nq++) {
            bf16x4 ov;
#pragma unroll
            for (int r = 0; r < 4; r++) ov[r] = (bf16_t)o[ct][nq][r];
            *(bf16x4*)(PBw + (nq * 16 + lo) * 64 +
                       (((2 * ct + (hi >> 1)) ^ lx) * 8) + (hi & 1) * 4) = ov;
        }
    __syncthreads();
    // ---- combine 4 slabs + 4 l's in fp32, normalize, store yob
    int head = bm % 12, b = bm / 12;
    bf16_t* yb = yob + (size_t)(b * 8 + f) * NSTRIDE + (size_t)(qs * 64) * 768 + head * 64;
#pragma unroll
    for (int i = 0; i < 2; i++) {
        int c = i * 256 + tid;              // [0,512) chunk: 64 rows x 8 chunks
        int row = c >> 3, j = c & 7;
        int off = row * 64 + ((j ^ (row & 7)) * 8);
        float invl = 1.0f / (Lsm[0][row] + Lsm[1][row] + Lsm[2][row] + Lsm[3][row]);
        bf16x8 p0 = *(const bf16x8*)(PBF[0] + off);
        bf16x8 p1 = *(const bf16x8*)(PBF[1] + off);
        bf16x8 p2 = *(const bf16x8*)(PBF[2] + off);
        bf16x8 p3 = *(const bf16x8*)(PBF[3] + off);
        bf16x8 o8;
#pragma unroll
        for (int r = 0; r < 8; r++)
            o8[r] = (bf16_t)(((float)p0[r] + (float)p1[r] + (float)p2[r] + (float)p3[r]) * invl);
        *(bf16x8*)(yb + (size_t)row * 768 + j * 8) = o8;
    }
}

// ---------------------------------------------------------------------------
// Proj GEMM via MFMA + mp_sum. XCD-remapped by n.
// v4: LDS-staged — port of the qkv-v3 structure that took qkv off the top-5
// (direct fragment loads are L1-segment bound; staging converts them to
// coalesced row reads + swizzled ds_read_b128). Tile 64(M)x128(P), BK=64,
// A 64x64 + B 128x64 = 24 KB LDS, same chunk^(row&7) swizzle both sides.
// ---------------------------------------------------------------------------
__global__ __launch_bounds__(256, 2) void va_proj_mfma(const bf16_t* __restrict__ Wb,
                                                       const bf16_t* __restrict__ yob,
                                                       const float* __restrict__ x,
                                                       float* __restrict__ out) {
    int idx = blockIdx.x;                   // [0,384)
    int n  = (idx & 7) + 8 * ((idx >> 3) & 1);
    int rest = idx >> 4;                    // [0,24)
    int p0 = (rest & 1) * 128;
    int m0 = (rest >> 1) * 64;              // [0,12)*64
    int tid = threadIdx.x;
    int lane = tid & 63, w = tid >> 6;      // w = column-slice index [0,4)
    int lo = lane & 15, hi = lane >> 4;
    int lx = lo & 7;

    __shared__ bf16_t Asm[64 * 64];         // [m 0..63][k 0..63]
    __shared__ bf16_t Bsm[128 * 64];        // [p 0..127][k 0..63]

    int srow = tid >> 3, schunk = tid & 7;  // srow in [0,32)
    const bf16_t* Ag = Wb + (size_t)(m0 + srow) * 768 + schunk * 8;
    const bf16_t* Bg = yob + (size_t)n * NSTRIDE + (size_t)(p0 + srow) * 768 + schunk * 8;
    int sdst = srow * 128 + ((schunk ^ (srow & 7)) << 4);

    f32x4 acc[4][2];
#pragma unroll
    for (int mt = 0; mt < 4; mt++)
#pragma unroll
        for (int nt = 0; nt < 2; nt++) acc[mt][nt] = (f32x4){0.f, 0.f, 0.f, 0.f};

    bf16x8 sa[2], sb[4];
    auto gload = [&](int k0) {
#pragma unroll
        for (int i = 0; i < 2; i++)
            sa[i] = *(const bf16x8*)(Ag + (size_t)i * 32 * 768 + k0);
#pragma unroll
        for (int i = 0; i < 4; i++)
            sb[i] = *(const bf16x8*)(Bg + (size_t)i * 32 * 768 + k0);
    };
    auto swrite = [&]() {
        char* Ac = (char*)Asm;
        char* Bc = (char*)Bsm;
#pragma unroll
        for (int i = 0; i < 2; i++)
            *(bf16x8*)(Ac + sdst + i * 32 * 128) = sa[i];
#pragma unroll
        for (int i = 0; i < 4; i++)
            *(bf16x8*)(Bc + sdst + i * 32 * 128) = sb[i];
    };

    gload(0);
    for (int s = 0; s < 12; s++) {
        __syncthreads();
        swrite();
        if (s < 11) gload((s + 1) * 64);
        __syncthreads();
#pragma unroll
        for (int kk = 0; kk < 64; kk += 32) {
            int cb = kk >> 3;
            bf16x8 af[4], bfr[2];
            const char* Ac = (const char*)Asm;
            const char* Bc = (const char*)Bsm;
#pragma unroll
            for (int mt = 0; mt < 4; mt++) {
                int row = mt * 16 + lo;
                af[mt] = *(const bf16x8*)(Ac + row * 128 + (((cb + hi) ^ lx) << 4));
            }
#pragma unroll
            for (int nt = 0; nt < 2; nt++) {
                int row = w * 32 + nt * 16 + lo;
                bfr[nt] = *(const bf16x8*)(Bc + row * 128 + (((cb + hi) ^ lx) << 4));
            }
#pragma unroll
            for (int mt = 0; mt < 4; mt++)
#pragma unroll
                for (int nt = 0; nt < 2; nt++)
                    acc[mt][nt] = __builtin_amdgcn_mfma_f32_16x16x32_bf16(af[mt], bfr[nt], acc[mt][nt], 0, 0, 0);
        }
    }

    const float* xn = x + (size_t)n * NSTRIDE;
    float* on = out + (size_t)n * NSTRIDE;
#pragma unroll
    for (int mt = 0; mt < 4; mt++)
#pragma unroll
        for (int nt = 0; nt < 2; nt++)
#pragma unroll
            for (int r = 0; r < 4; r++) {
                int oo = m0 + mt * 16 + hi * 4 + r;
                int p  = p0 + w * 32 + nt * 16 + lo;
                size_t idx2 = (size_t)oo * 256 + p;
                on[idx2] = (xn[idx2] * 0.7f + acc[mt][nt][r] * 0.3f) * 1.3130643f;
            }
}

// ---------------------------------------------------------------------------
extern "C" void kernel_launch(void* const* d_in, const int* in_sizes, int n_in,
                              void* d_out, int out_size, void* d_ws, size_t ws_size,
                              hipStream_t stream) {
    const float* x     = (const float*)d_in[0];
    const float* wqkv  = (const float*)d_in[1];
    const float* wproj = (const float*)d_in[2];
    float* out = (float*)d_out;

    // Workspace layout kept identical to v8 (Opart/lpart slots now unused).
    bf16_t* Opart = (bf16_t*)d_ws;                             // (unused)
    float*  lpart = (float*)(Opart + (size_t)24 * 36 * 16384); // (unused)
    bf16_t* wqkv_nb  = (bf16_t*)(lpart + (size_t)24 * 36 * 256);
    bf16_t* xt       = wqkv_nb + (size_t)3072 * 768;
    bf16_t* qkvb     = xt + NSTRIDE * 16;
    bf16_t* yob      = qkvb + 3 * QKV_ONE;

    va_prep<<<6144, 256, 0, stream>>>(wqkv, wproj, x, wqkv_nb, xt);
    va_qkv_mfma<<<576, 256, 0, stream>>>(wqkv_nb, xt, qkvb);
    va_attn<<<768, 256, 0, stream>>>(qkvb, yob);
    va_proj_mfma<<<384, 256, 0, stream>>>(wqkv_nb + (size_t)2304 * 768, yob, x, out);
}